// Round 1
// baseline (695.849 us; speedup 1.0000x reference)
//
#include <hip/hip_runtime.h>
#include <hip/hip_bf16.h>

#define B_   8
#define T_   2048
#define EMB_ 1024
#define ND_  1024

typedef __attribute__((ext_vector_type(8))) short   bf8_t;   // 8 bf16 elements (4 VGPRs)
typedef __attribute__((ext_vector_type(4))) float   f32x4;

__device__ __forceinline__ unsigned short f2bf(float f) {
  union { float f; unsigned int u; } c; c.f = f;
  unsigned int u = c.u;
  unsigned int r = (u + 0x7FFFu + ((u >> 16) & 1u)) >> 16;
  return (unsigned short)r;
}

__device__ __forceinline__ void gload_lds16(const unsigned short* g, unsigned short* l) {
  __builtin_amdgcn_global_load_lds(
      (const __attribute__((address_space(1))) unsigned int*)g,
      (__attribute__((address_space(3))) unsigned int*)l,
      16, 0, 0);
}

// Stage a 128x32 bf16 tile (rows x k) from global (row stride = lda elems) into
// linear LDS [128][32]. 8 KB = 8 wave-chunks of 1 KB; wave w covers chunks 2w, 2w+1.
__device__ __forceinline__ void stage128x32(const unsigned short* __restrict__ g,
                                            int lda, unsigned short* lds,
                                            int wave, int lane) {
  const int rsub = lane >> 2;          // row within 16-row chunk
  const int koff = (lane & 3) * 8;     // element offset within row
#pragma unroll
  for (int c = 0; c < 2; ++c) {
    const int chunk = wave * 2 + c;    // wave-uniform
    const unsigned short* src = g + (size_t)(chunk * 16 + rsub) * lda + koff;
    gload_lds16(src, lds + chunk * 512);
  }
}

// One BK=32 step: each wave does its 4x4 grid of 16x16x32 MFMAs.
__device__ __forceinline__ void mfma_step(const unsigned short* As, const unsigned short* Bs,
                                          f32x4 acc[4][4], int lane, int wm, int wn) {
  const int r = lane & 15, k8 = (lane >> 4) * 8;
  bf8_t a[4], b[4];
#pragma unroll
  for (int m = 0; m < 4; ++m)
    a[m] = *(const bf8_t*)(As + (size_t)(wm * 64 + m * 16 + r) * 32 + k8);
#pragma unroll
  for (int n = 0; n < 4; ++n)
    b[n] = *(const bf8_t*)(Bs + (size_t)(wn * 64 + n * 16 + r) * 32 + k8);
#pragma unroll
  for (int m = 0; m < 4; ++m)
#pragma unroll
    for (int n = 0; n < 4; ++n)
      acc[m][n] = __builtin_amdgcn_mfma_f32_16x16x32_bf16(a[m], b[n], acc[m][n], 0, 0, 0);
}

__device__ __forceinline__ void zero_acc(f32x4 acc[4][4]) {
#pragma unroll
  for (int m = 0; m < 4; ++m)
#pragma unroll
    for (int n = 0; n < 4; ++n)
#pragma unroll
      for (int q = 0; q < 4; ++q) acc[m][n][q] = 0.f;
}

// ---------------- X -> bf16 ----------------
__global__ void __launch_bounds__(256) cvt_x_kernel(const float* __restrict__ in,
                                                    unsigned short* __restrict__ out) {
  const int i = (blockIdx.x * 256 + threadIdx.x) * 4;
  float4 v = *(const float4*)(in + i);
  ushort4 o = make_ushort4(f2bf(v.x), f2bf(v.y), f2bf(v.z), f2bf(v.w));
  *(ushort4*)(out + i) = o;
}

// ---------------- W [K][N] f32 -> Wt [N][K] bf16 (optionally scaled) ----------------
__global__ void __launch_bounds__(256) transpose_w_kernel(const float* __restrict__ W,
                                                          unsigned short* __restrict__ Wt,
                                                          float cscale) {
  __shared__ unsigned short tile[32][33];
  const int n0 = blockIdx.x * 32, k0 = blockIdx.y * 32;
  const int tx = threadIdx.x & 31, ty = threadIdx.x >> 5;  // 32 x 8
#pragma unroll
  for (int r = 0; r < 32; r += 8) {
    float v = W[(size_t)(k0 + ty + r) * ND_ + n0 + tx];
    tile[tx][ty + r] = f2bf(v * cscale);
  }
  __syncthreads();
#pragma unroll
  for (int r = 0; r < 32; r += 8) {
    Wt[(size_t)(n0 + ty + r) * EMB_ + k0 + tx] = tile[ty + r][tx];
  }
}

// ---------------- projection GEMM: C = A @ Bt^T ----------------
// A: [16384][1024] bf16, Bt: [1024][1024] bf16 ([n][k]).
// OUTMODE 0: C bf16 [16384][1024].  OUTMODE 1: V transposed -> Vt[b][n][t] bf16.
template <int OUTMODE>
__global__ void __launch_bounds__(256) gemm_xw_kernel(const unsigned short* __restrict__ A,
                                                      const unsigned short* __restrict__ Bt,
                                                      unsigned short* __restrict__ C) {
  __shared__ unsigned short As[128 * 32], Bs[128 * 32];
  const int tid = threadIdx.x, lane = tid & 63, wave = tid >> 6;
  const int wm = wave >> 1, wn = wave & 1;
  const int m0 = blockIdx.y * 128, n0 = blockIdx.x * 128;
  const unsigned short* Ab = A + (size_t)m0 * EMB_;
  const unsigned short* Bb = Bt + (size_t)n0 * EMB_;
  f32x4 acc[4][4];
  zero_acc(acc);
  for (int k = 0; k < EMB_; k += 32) {
    __syncthreads();
    stage128x32(Ab + k, EMB_, As, wave, lane);
    stage128x32(Bb + k, EMB_, Bs, wave, lane);
    __syncthreads();
    mfma_step(As, Bs, acc, lane, wm, wn);
  }
  const int cr = ((lane >> 4) << 2), cc = lane & 15;
#pragma unroll
  for (int m = 0; m < 4; ++m)
#pragma unroll
    for (int n = 0; n < 4; ++n)
#pragma unroll
      for (int q = 0; q < 4; ++q) {
        const int row = m0 + wm * 64 + m * 16 + cr + q;
        const int col = n0 + wn * 64 + n * 16 + cc;
        const unsigned short val = f2bf(acc[m][n][q]);
        if (OUTMODE == 0) {
          C[(size_t)row * ND_ + col] = val;
        } else {
          const int b = row >> 11, t = row & 2047;
          C[((size_t)b * ND_ + col) * T_ + t] = val;
        }
      }
}

// ---------------- column stats: m_s, 1/l_s over t >= s ----------------
__global__ void __launch_bounds__(256) colstats_kernel(const unsigned short* __restrict__ Qb,
                                                       const unsigned short* __restrict__ Kb,
                                                       float* __restrict__ colmax,
                                                       float* __restrict__ colinv) {
  __shared__ unsigned short As[128 * 32], Bs[128 * 32];
  __shared__ float redm[2][2][4][16], redl[2][2][4][16];
  const int sblk = blockIdx.x, b = blockIdx.y;
  const int tid = threadIdx.x, lane = tid & 63, wave = tid >> 6;
  const int wm = wave >> 1, wn = wave & 1;
  const int s0 = sblk * 128;
  const unsigned short* Qbase = Qb + (size_t)b * T_ * ND_;
  const unsigned short* Kbase = Kb + ((size_t)b * T_ + s0) * ND_;
  const int cr = ((lane >> 4) << 2), cc = lane & 15;
  float rm[4], rl[4];
#pragma unroll
  for (int n = 0; n < 4; ++n) { rm[n] = -1e30f; rl[n] = 0.f; }

  for (int t0 = s0; t0 < T_; t0 += 128) {
    f32x4 acc[4][4];
    zero_acc(acc);
    const unsigned short* Ab = Qbase + (size_t)t0 * ND_;
    for (int k = 0; k < ND_; k += 32) {
      __syncthreads();
      stage128x32(Ab + k, ND_, As, wave, lane);
      stage128x32(Kbase + k, ND_, Bs, wave, lane);
      __syncthreads();
      mfma_step(As, Bs, acc, lane, wm, wn);
    }
#pragma unroll
    for (int n = 0; n < 4; ++n) {
      const int s = s0 + wn * 64 + n * 16 + cc;
#pragma unroll
      for (int m = 0; m < 4; ++m)
#pragma unroll
        for (int q = 0; q < 4; ++q) {
          const int t = t0 + wm * 64 + m * 16 + cr + q;
          if (t >= s) {
            const float v = acc[m][n][q];
            const float mm = fmaxf(rm[n], v);
            rl[n] = rl[n] * __expf(rm[n] - mm) + __expf(v - mm);
            rm[n] = mm;
          }
        }
    }
  }
  // reduce across the 4 lane-groups (rows) of the wave
#pragma unroll
  for (int n = 0; n < 4; ++n) {
#pragma unroll
    for (int off = 16; off < 64; off <<= 1) {
      const float om = __shfl_xor(rm[n], off);
      const float ol = __shfl_xor(rl[n], off);
      const float mm = fmaxf(rm[n], om);
      rl[n] = rl[n] * __expf(rm[n] - mm) + ol * __expf(om - mm);
      rm[n] = mm;
    }
  }
  __syncthreads();
  if (lane < 16) {
#pragma unroll
    for (int n = 0; n < 4; ++n) { redm[wm][wn][n][lane] = rm[n]; redl[wm][wn][n][lane] = rl[n]; }
  }
  __syncthreads();
  if (wm == 0 && lane < 16) {
#pragma unroll
    for (int n = 0; n < 4; ++n) {
      const float m0v = redm[0][wn][n][lane], l0v = redl[0][wn][n][lane];
      const float m1v = redm[1][wn][n][lane], l1v = redl[1][wn][n][lane];
      const float mm = fmaxf(m0v, m1v);
      const float ll = l0v * __expf(m0v - mm) + l1v * __expf(m1v - mm);
      const int s = s0 + wn * 64 + n * 16 + lane;
      colmax[(size_t)b * T_ + s] = mm;
      colinv[(size_t)b * T_ + s] = 1.0f / ll;
    }
  }
}

// ---------------- P = exp(S - m_s) * inv_l_s (bf16), lower-triangle tiles ----------------
__global__ void __launch_bounds__(256) computep_kernel(const unsigned short* __restrict__ Qb,
                                                       const unsigned short* __restrict__ Kb,
                                                       const float* __restrict__ colmax,
                                                       const float* __restrict__ colinv,
                                                       unsigned short* __restrict__ Pb) {
  const int sblk = blockIdx.x, tblk = blockIdx.y, b = blockIdx.z;
  if (tblk < sblk) return;  // strictly-upper tiles are never read
  __shared__ unsigned short As[128 * 32], Bs[128 * 32];
  const int tid = threadIdx.x, lane = tid & 63, wave = tid >> 6;
  const int wm = wave >> 1, wn = wave & 1;
  const int t0 = tblk * 128, s0 = sblk * 128;
  const unsigned short* Qbase = Qb + ((size_t)b * T_ + t0) * ND_;
  const unsigned short* Kbase = Kb + ((size_t)b * T_ + s0) * ND_;
  f32x4 acc[4][4];
  zero_acc(acc);
  for (int k = 0; k < ND_; k += 32) {
    __syncthreads();
    stage128x32(Qbase + k, ND_, As, wave, lane);
    stage128x32(Kbase + k, ND_, Bs, wave, lane);
    __syncthreads();
    mfma_step(As, Bs, acc, lane, wm, wn);
  }
  const int cr = ((lane >> 4) << 2), cc = lane & 15;
  unsigned short* Pbase = Pb + (size_t)b * T_ * T_;
#pragma unroll
  for (int n = 0; n < 4; ++n) {
    const int s = s0 + wn * 64 + n * 16 + cc;
    const float ms = colmax[(size_t)b * T_ + s];
    const float inv = colinv[(size_t)b * T_ + s];
#pragma unroll
    for (int m = 0; m < 4; ++m)
#pragma unroll
      for (int q = 0; q < 4; ++q) {
        const int t = t0 + wm * 64 + m * 16 + cr + q;
        float p = 0.f;
        if (t >= s) p = __expf(acc[m][n][q] - ms) * inv;
        Pbase[(size_t)t * T_ + s] = f2bf(p);
      }
  }
}

// ---------------- out = P @ V  (A = Pb [T][T] bf16, Bt = Vt [ND][T] bf16, C f32) ----------------
__global__ void __launch_bounds__(256) gemm_pv_kernel(const unsigned short* __restrict__ Pb,
                                                      const unsigned short* __restrict__ Vt,
                                                      float* __restrict__ out) {
  __shared__ unsigned short As[128 * 32], Bs[128 * 32];
  const int nblk = blockIdx.x, tblk = blockIdx.y, b = blockIdx.z;
  const int tid = threadIdx.x, lane = tid & 63, wave = tid >> 6;
  const int wm = wave >> 1, wn = wave & 1;
  const int m0 = tblk * 128, n0 = nblk * 128;
  const unsigned short* Ab = Pb + (size_t)b * T_ * T_ + (size_t)m0 * T_;
  const unsigned short* Bb = Vt + (size_t)b * ND_ * T_ + (size_t)n0 * T_;
  f32x4 acc[4][4];
  zero_acc(acc);
  const int kmax = m0 + 128;  // P[t][s] == 0 for s > t handled by stored zeros
  for (int k = 0; k < kmax; k += 32) {
    __syncthreads();
    stage128x32(Ab + k, T_, As, wave, lane);
    stage128x32(Bb + k, T_, Bs, wave, lane);
    __syncthreads();
    mfma_step(As, Bs, acc, lane, wm, wn);
  }
  float* Cb = out + (size_t)b * T_ * ND_;
  const int cr = ((lane >> 4) << 2), cc = lane & 15;
#pragma unroll
  for (int m = 0; m < 4; ++m)
#pragma unroll
    for (int n = 0; n < 4; ++n)
#pragma unroll
      for (int q = 0; q < 4; ++q) {
        const int row = m0 + wm * 64 + m * 16 + cr + q;
        const int col = n0 + wn * 64 + n * 16 + cc;
        Cb[(size_t)row * ND_ + col] = acc[m][n][q];
      }
}

extern "C" void kernel_launch(void* const* d_in, const int* in_sizes, int n_in,
                              void* d_out, int out_size, void* d_ws, size_t ws_size,
                              hipStream_t stream) {
  const float* X  = (const float*)d_in[0];
  const float* Wq = (const float*)d_in[1];
  const float* Wk = (const float*)d_in[2];
  const float* Wv = (const float*)d_in[3];
  float* out = (float*)d_out;
  (void)in_sizes; (void)n_in; (void)out_size;

  char* ws = (char*)d_ws;
  size_t off = 0;
  auto alloc = [&](size_t bytes) {
    void* p = ws + off;
    off += (bytes + 255) & ~(size_t)255;
    return p;
  };
  unsigned short* Xb  = (unsigned short*)alloc((size_t)B_ * T_ * EMB_ * 2);
  unsigned short* Wtq = (unsigned short*)alloc((size_t)ND_ * EMB_ * 2);
  unsigned short* Wtk = (unsigned short*)alloc((size_t)ND_ * EMB_ * 2);
  unsigned short* Wtv = (unsigned short*)alloc((size_t)ND_ * EMB_ * 2);
  unsigned short* Qb  = (unsigned short*)alloc((size_t)B_ * T_ * ND_ * 2);
  unsigned short* Kb  = (unsigned short*)alloc((size_t)B_ * T_ * ND_ * 2);
  unsigned short* Vt  = (unsigned short*)alloc((size_t)B_ * ND_ * T_ * 2);
  float* colmax = (float*)alloc((size_t)B_ * T_ * 4);
  float* colinv = (float*)alloc((size_t)B_ * T_ * 4);
  unsigned short* Pb  = (unsigned short*)alloc((size_t)B_ * T_ * T_ * 2);
  if (off > ws_size) return;  // workspace too small -> fail visibly

  hipLaunchKernelGGL(cvt_x_kernel, dim3((B_ * T_ * EMB_) / 1024), dim3(256), 0, stream, X, Xb);
  hipLaunchKernelGGL(transpose_w_kernel, dim3(32, 32), dim3(256), 0, stream, Wq, Wtq, 0.03125f);
  hipLaunchKernelGGL(transpose_w_kernel, dim3(32, 32), dim3(256), 0, stream, Wk, Wtk, 1.0f);
  hipLaunchKernelGGL(transpose_w_kernel, dim3(32, 32), dim3(256), 0, stream, Wv, Wtv, 1.0f);
  hipLaunchKernelGGL((gemm_xw_kernel<0>), dim3(ND_ / 128, (B_ * T_) / 128), dim3(256), 0, stream, Xb, Wtq, Qb);
  hipLaunchKernelGGL((gemm_xw_kernel<0>), dim3(ND_ / 128, (B_ * T_) / 128), dim3(256), 0, stream, Xb, Wtk, Kb);
  hipLaunchKernelGGL((gemm_xw_kernel<1>), dim3(ND_ / 128, (B_ * T_) / 128), dim3(256), 0, stream, Xb, Wtv, Vt);
  hipLaunchKernelGGL(colstats_kernel, dim3(T_ / 128, B_), dim3(256), 0, stream, Qb, Kb, colmax, colinv);
  hipLaunchKernelGGL(computep_kernel, dim3(T_ / 128, T_ / 128, B_), dim3(256), 0, stream, Qb, Kb, colmax, colinv, Pb);
  hipLaunchKernelGGL(gemm_pv_kernel, dim3(ND_ / 128, T_ / 128, B_), dim3(256), 0, stream, Pb, Vt, out);
}

// Round 2
// 404.562 us; speedup vs baseline: 1.7200x; 1.7200x over previous
//
#include <hip/hip_runtime.h>
#include <hip/hip_bf16.h>

#define B_   8
#define T_   2048
#define EMB_ 1024
#define ND_  1024
#define NTB  16   // T_/128

typedef __attribute__((ext_vector_type(8))) short   bf8_t;   // 8 bf16 elements (4 VGPRs)
typedef __attribute__((ext_vector_type(4))) float   f32x4;

__device__ __forceinline__ unsigned short f2bf(float f) {
  union { float f; unsigned int u; } c; c.f = f;
  unsigned int u = c.u;
  unsigned int r = (u + 0x7FFFu + ((u >> 16) & 1u)) >> 16;
  return (unsigned short)r;
}

__device__ __forceinline__ float bf2f(unsigned short b) {
  union { unsigned int u; float f; } c; c.u = ((unsigned int)b) << 16;
  return c.f;
}

__device__ __forceinline__ void gload_lds16(const unsigned short* g, unsigned short* l) {
  __builtin_amdgcn_global_load_lds(
      (const __attribute__((address_space(1))) unsigned int*)g,
      (__attribute__((address_space(3))) unsigned int*)l,
      16, 0, 0);
}

// Stage a 128x32 bf16 tile (rows x k) from global (row stride = lda elems) into
// linear LDS [128][32]. 8 KB = 8 wave-chunks of 1 KB; wave w covers chunks 2w, 2w+1.
__device__ __forceinline__ void stage128x32(const unsigned short* __restrict__ g,
                                            int lda, unsigned short* lds,
                                            int wave, int lane) {
  const int rsub = lane >> 2;          // row within 16-row chunk
  const int koff = (lane & 3) * 8;     // element offset within row
#pragma unroll
  for (int c = 0; c < 2; ++c) {
    const int chunk = wave * 2 + c;    // wave-uniform
    const unsigned short* src = g + (size_t)(chunk * 16 + rsub) * lda + koff;
    gload_lds16(src, lds + chunk * 512);
  }
}

// One BK=32 step: each wave does its 4x4 grid of 16x16x32 MFMAs.
__device__ __forceinline__ void mfma_step(const unsigned short* As, const unsigned short* Bs,
                                          f32x4 acc[4][4], int lane, int wm, int wn) {
  const int r = lane & 15, k8 = (lane >> 4) * 8;
  bf8_t a[4], b[4];
#pragma unroll
  for (int m = 0; m < 4; ++m)
    a[m] = *(const bf8_t*)(As + (size_t)(wm * 64 + m * 16 + r) * 32 + k8);
#pragma unroll
  for (int n = 0; n < 4; ++n)
    b[n] = *(const bf8_t*)(Bs + (size_t)(wn * 64 + n * 16 + r) * 32 + k8);
#pragma unroll
  for (int m = 0; m < 4; ++m)
#pragma unroll
    for (int n = 0; n < 4; ++n)
      acc[m][n] = __builtin_amdgcn_mfma_f32_16x16x32_bf16(a[m], b[n], acc[m][n], 0, 0, 0);
}

__device__ __forceinline__ void zero_acc(f32x4 acc[4][4]) {
#pragma unroll
  for (int m = 0; m < 4; ++m)
#pragma unroll
    for (int n = 0; n < 4; ++n)
#pragma unroll
      for (int q = 0; q < 4; ++q) acc[m][n][q] = 0.f;
}

// ---------------- X -> bf16 ----------------
__global__ void __launch_bounds__(256) cvt_x_kernel(const float* __restrict__ in,
                                                    unsigned short* __restrict__ out) {
  const int i = (blockIdx.x * 256 + threadIdx.x) * 4;
  float4 v = *(const float4*)(in + i);
  ushort4 o = make_ushort4(f2bf(v.x), f2bf(v.y), f2bf(v.z), f2bf(v.w));
  *(ushort4*)(out + i) = o;
}

// ---------------- W [K][N] f32 -> Wt [N][K] bf16 (optionally scaled) ----------------
__global__ void __launch_bounds__(256) transpose_w_kernel(const float* __restrict__ W,
                                                          unsigned short* __restrict__ Wt,
                                                          float cscale) {
  __shared__ unsigned short tile[32][33];
  const int n0 = blockIdx.x * 32, k0 = blockIdx.y * 32;
  const int tx = threadIdx.x & 31, ty = threadIdx.x >> 5;  // 32 x 8
#pragma unroll
  for (int r = 0; r < 32; r += 8) {
    float v = W[(size_t)(k0 + ty + r) * ND_ + n0 + tx];
    tile[tx][ty + r] = f2bf(v * cscale);
  }
  __syncthreads();
#pragma unroll
  for (int r = 0; r < 32; r += 8) {
    Wt[(size_t)(n0 + ty + r) * EMB_ + k0 + tx] = tile[ty + r][tx];
  }
}

// ---------------- projection GEMM: C = A @ Bt^T ----------------
// A: [16384][1024] bf16, Bt: [1024][1024] bf16 ([n][k]).
// OUTMODE 0: C bf16 [16384][1024].  OUTMODE 1: V transposed -> Vt[b][n][t] bf16.
template <int OUTMODE>
__global__ void __launch_bounds__(256) gemm_xw_kernel(const unsigned short* __restrict__ A,
                                                      const unsigned short* __restrict__ Bt,
                                                      unsigned short* __restrict__ C) {
  __shared__ unsigned short As[128 * 32], Bs[128 * 32];
  const int tid = threadIdx.x, lane = tid & 63, wave = tid >> 6;
  const int wm = wave >> 1, wn = wave & 1;
  const int m0 = blockIdx.y * 128, n0 = blockIdx.x * 128;
  const unsigned short* Ab = A + (size_t)m0 * EMB_;
  const unsigned short* Bb = Bt + (size_t)n0 * EMB_;
  f32x4 acc[4][4];
  zero_acc(acc);
  for (int k = 0; k < EMB_; k += 32) {
    __syncthreads();
    stage128x32(Ab + k, EMB_, As, wave, lane);
    stage128x32(Bb + k, EMB_, Bs, wave, lane);
    __syncthreads();
    mfma_step(As, Bs, acc, lane, wm, wn);
  }
  const int cr = ((lane >> 4) << 2), cc = lane & 15;
#pragma unroll
  for (int m = 0; m < 4; ++m)
#pragma unroll
    for (int n = 0; n < 4; ++n)
#pragma unroll
      for (int q = 0; q < 4; ++q) {
        const int row = m0 + wm * 64 + m * 16 + cr + q;
        const int col = n0 + wn * 64 + n * 16 + cc;
        const unsigned short val = f2bf(acc[m][n][q]);
        if (OUTMODE == 0) {
          C[(size_t)row * ND_ + col] = val;
        } else {
          const int b = row >> 11, t = row & 2047;
          C[((size_t)b * ND_ + col) * T_ + t] = val;
        }
      }
}

// ---------------- S tiles (lower triangle) + per-tile column partial stats ----------------
// Writes S (bf16-rounded, scaled) into Sb[t][s]; partial column max/sumexp into pm/pl
// indexed [b][sblk][tblk][128].
__global__ void __launch_bounds__(256) scoretile_kernel(const unsigned short* __restrict__ Qb,
                                                        const unsigned short* __restrict__ Kb,
                                                        unsigned short* __restrict__ Sb,
                                                        float* __restrict__ pm,
                                                        float* __restrict__ pl) {
  const int sblk = blockIdx.x, tblk = blockIdx.y, b = blockIdx.z;
  if (tblk < sblk) return;
  __shared__ unsigned short As[128 * 32], Bs[128 * 32];
  __shared__ float redm[2][2][4][16], redl[2][2][4][16];
  const int tid = threadIdx.x, lane = tid & 63, wave = tid >> 6;
  const int wm = wave >> 1, wn = wave & 1;
  const int t0 = tblk * 128, s0 = sblk * 128;
  const unsigned short* Qbase = Qb + ((size_t)b * T_ + t0) * ND_;
  const unsigned short* Kbase = Kb + ((size_t)b * T_ + s0) * ND_;
  f32x4 acc[4][4];
  zero_acc(acc);
  for (int k = 0; k < ND_; k += 32) {
    __syncthreads();
    stage128x32(Qbase + k, ND_, As, wave, lane);
    stage128x32(Kbase + k, ND_, Bs, wave, lane);
    __syncthreads();
    mfma_step(As, Bs, acc, lane, wm, wn);
  }
  const int cr = ((lane >> 4) << 2), cc = lane & 15;
  unsigned short* Pbase = Sb + (size_t)b * T_ * T_;
  const bool diag = (tblk == sblk);
  float rm[4], rl[4];
#pragma unroll
  for (int n = 0; n < 4; ++n) { rm[n] = -1e30f; rl[n] = 0.f; }
#pragma unroll
  for (int n = 0; n < 4; ++n) {
    const int s = s0 + wn * 64 + n * 16 + cc;
#pragma unroll
    for (int m = 0; m < 4; ++m)
#pragma unroll
      for (int q = 0; q < 4; ++q) {
        const int t = t0 + wm * 64 + m * 16 + cr + q;
        if (!diag || t >= s) {
          const unsigned short bv = f2bf(acc[m][n][q]);
          Pbase[(size_t)t * T_ + s] = bv;
          const float v = bf2f(bv);  // stats from the rounded value -> consistent with pscale
          const float mm = fmaxf(rm[n], v);
          rl[n] = rl[n] * __expf(rm[n] - mm) + __expf(v - mm);
          rm[n] = mm;
        }
      }
  }
  // reduce across the 4 row-groups of the wave
#pragma unroll
  for (int n = 0; n < 4; ++n) {
#pragma unroll
    for (int off = 16; off < 64; off <<= 1) {
      const float om = __shfl_xor(rm[n], off);
      const float ol = __shfl_xor(rl[n], off);
      const float mm = fmaxf(rm[n], om);
      rl[n] = rl[n] * __expf(rm[n] - mm) + ol * __expf(om - mm);
      rm[n] = mm;
    }
  }
  __syncthreads();
  if (lane < 16) {
#pragma unroll
    for (int n = 0; n < 4; ++n) { redm[wm][wn][n][lane] = rm[n]; redl[wm][wn][n][lane] = rl[n]; }
  }
  __syncthreads();
  if (wm == 0 && lane < 16) {
    const size_t base = (((size_t)b * NTB + sblk) * NTB + tblk) * 128;
#pragma unroll
    for (int n = 0; n < 4; ++n) {
      const float m0v = redm[0][wn][n][lane], l0v = redl[0][wn][n][lane];
      const float m1v = redm[1][wn][n][lane], l1v = redl[1][wn][n][lane];
      const float mm = fmaxf(m0v, m1v);
      const float ll = l0v * __expf(m0v - mm) + l1v * __expf(m1v - mm);
      pm[base + wn * 64 + n * 16 + lane] = mm;
      pl[base + wn * 64 + n * 16 + lane] = ll;
    }
  }
}

// ---------------- fold per-tile partials into colmax / colinv ----------------
__global__ void __launch_bounds__(128) colreduce_kernel(const float* __restrict__ pm,
                                                        const float* __restrict__ pl,
                                                        float* __restrict__ colmax,
                                                        float* __restrict__ colinv) {
  const int sblk = blockIdx.x, b = blockIdx.y, c = threadIdx.x;
  float m = -1e30f, l = 0.f;
  for (int tblk = sblk; tblk < NTB; ++tblk) {
    const size_t base = (((size_t)b * NTB + sblk) * NTB + tblk) * 128;
    const float om = pm[base + c], ol = pl[base + c];
    const float mm = fmaxf(m, om);
    l = l * __expf(m - mm) + ol * __expf(om - mm);
    m = mm;
  }
  colmax[(size_t)b * T_ + sblk * 128 + c] = m;
  colinv[(size_t)b * T_ + sblk * 128 + c] = 1.0f / l;
}

// ---------------- P = exp(S - m_s) * inv_l_s, in place over lower-triangle tiles ----------------
__global__ void __launch_bounds__(256) pscale_kernel(unsigned short* __restrict__ Pb,
                                                     const float* __restrict__ colmax,
                                                     const float* __restrict__ colinv) {
  const int sblk = blockIdx.x, tblk = blockIdx.y, b = blockIdx.z;
  if (tblk < sblk) return;
  const int s0 = sblk * 128, t0 = tblk * 128;
  const int tid = threadIdx.x;
  const int col8 = (tid & 15) * 8;   // 8 consecutive columns per thread
  const int rbase = tid >> 4;        // 16 rows per pass
  unsigned short* Pbase = Pb + (size_t)b * T_ * T_;
  float ms[8], inv[8];
#pragma unroll
  for (int j = 0; j < 8; ++j) {
    ms[j]  = colmax[(size_t)b * T_ + s0 + col8 + j];
    inv[j] = colinv[(size_t)b * T_ + s0 + col8 + j];
  }
  const bool diag = (tblk == sblk);
  for (int r = rbase; r < 128; r += 16) {
    const int t = t0 + r;
    unsigned short* p = Pbase + (size_t)t * T_ + s0 + col8;
    bf8_t v = *(bf8_t*)p;
#pragma unroll
    for (int j = 0; j < 8; ++j) {
      float pv = 0.f;
      if (!diag || t >= s0 + col8 + j) {
        pv = __expf(bf2f((unsigned short)v[j]) - ms[j]) * inv[j];
      }
      v[j] = (short)f2bf(pv);
    }
    *(bf8_t*)p = v;
  }
}

// ---------------- out = P @ V  (A = Pb [T][T] bf16, Bt = Vt [ND][T] bf16, C f32) ----------------
__global__ void __launch_bounds__(256) gemm_pv_kernel(const unsigned short* __restrict__ Pb,
                                                      const unsigned short* __restrict__ Vt,
                                                      float* __restrict__ out) {
  __shared__ unsigned short As[128 * 32], Bs[128 * 32];
  const int nblk = blockIdx.x, tblk = blockIdx.y, b = blockIdx.z;
  const int tid = threadIdx.x, lane = tid & 63, wave = tid >> 6;
  const int wm = wave >> 1, wn = wave & 1;
  const int m0 = tblk * 128, n0 = nblk * 128;
  const unsigned short* Ab = Pb + (size_t)b * T_ * T_ + (size_t)m0 * T_;
  const unsigned short* Bb = Vt + (size_t)b * ND_ * T_ + (size_t)n0 * T_;
  f32x4 acc[4][4];
  zero_acc(acc);
  const int kmax = m0 + 128;  // P[t][s] == 0 for s > t handled by stored zeros
  for (int k = 0; k < kmax; k += 32) {
    __syncthreads();
    stage128x32(Ab + k, T_, As, wave, lane);
    stage128x32(Bb + k, T_, Bs, wave, lane);
    __syncthreads();
    mfma_step(As, Bs, acc, lane, wm, wn);
  }
  float* Cb = out + (size_t)b * T_ * ND_;
  const int cr = ((lane >> 4) << 2), cc = lane & 15;
#pragma unroll
  for (int m = 0; m < 4; ++m)
#pragma unroll
    for (int n = 0; n < 4; ++n)
#pragma unroll
      for (int q = 0; q < 4; ++q) {
        const int row = m0 + wm * 64 + m * 16 + cr + q;
        const int col = n0 + wn * 64 + n * 16 + cc;
        Cb[(size_t)row * ND_ + col] = acc[m][n][q];
      }
}

extern "C" void kernel_launch(void* const* d_in, const int* in_sizes, int n_in,
                              void* d_out, int out_size, void* d_ws, size_t ws_size,
                              hipStream_t stream) {
  const float* X  = (const float*)d_in[0];
  const float* Wq = (const float*)d_in[1];
  const float* Wk = (const float*)d_in[2];
  const float* Wv = (const float*)d_in[3];
  float* out = (float*)d_out;
  (void)in_sizes; (void)n_in; (void)out_size;

  char* ws = (char*)d_ws;
  size_t off = 0;
  auto alloc = [&](size_t bytes) {
    void* p = ws + off;
    off += (bytes + 255) & ~(size_t)255;
    return p;
  };
  unsigned short* Xb  = (unsigned short*)alloc((size_t)B_ * T_ * EMB_ * 2);
  unsigned short* Wtq = (unsigned short*)alloc((size_t)ND_ * EMB_ * 2);
  unsigned short* Wtk = (unsigned short*)alloc((size_t)ND_ * EMB_ * 2);
  unsigned short* Wtv = (unsigned short*)alloc((size_t)ND_ * EMB_ * 2);
  unsigned short* Qb  = (unsigned short*)alloc((size_t)B_ * T_ * ND_ * 2);
  unsigned short* Kb  = (unsigned short*)alloc((size_t)B_ * T_ * ND_ * 2);
  unsigned short* Vt  = (unsigned short*)alloc((size_t)B_ * ND_ * T_ * 2);
  float* colmax = (float*)alloc((size_t)B_ * T_ * 4);
  float* colinv = (float*)alloc((size_t)B_ * T_ * 4);
  float* pm     = (float*)alloc((size_t)B_ * NTB * NTB * 128 * 4);
  float* pl     = (float*)alloc((size_t)B_ * NTB * NTB * 128 * 4);
  unsigned short* Pb  = (unsigned short*)alloc((size_t)B_ * T_ * T_ * 2);
  if (off > ws_size) return;  // workspace too small -> fail visibly

  hipLaunchKernelGGL(cvt_x_kernel, dim3((B_ * T_ * EMB_) / 1024), dim3(256), 0, stream, X, Xb);
  hipLaunchKernelGGL(transpose_w_kernel, dim3(32, 32), dim3(256), 0, stream, Wq, Wtq, 0.03125f);
  hipLaunchKernelGGL(transpose_w_kernel, dim3(32, 32), dim3(256), 0, stream, Wk, Wtk, 1.0f);
  hipLaunchKernelGGL(transpose_w_kernel, dim3(32, 32), dim3(256), 0, stream, Wv, Wtv, 1.0f);
  hipLaunchKernelGGL((gemm_xw_kernel<0>), dim3(ND_ / 128, (B_ * T_) / 128), dim3(256), 0, stream, Xb, Wtq, Qb);
  hipLaunchKernelGGL((gemm_xw_kernel<0>), dim3(ND_ / 128, (B_ * T_) / 128), dim3(256), 0, stream, Xb, Wtk, Kb);
  hipLaunchKernelGGL((gemm_xw_kernel<1>), dim3(ND_ / 128, (B_ * T_) / 128), dim3(256), 0, stream, Xb, Wtv, Vt);
  hipLaunchKernelGGL(scoretile_kernel, dim3(NTB, NTB, B_), dim3(256), 0, stream, Qb, Kb, Pb, pm, pl);
  hipLaunchKernelGGL(colreduce_kernel, dim3(NTB, B_), dim3(128), 0, stream, pm, pl, colmax, colinv);
  hipLaunchKernelGGL(pscale_kernel, dim3(NTB, NTB, B_), dim3(256), 0, stream, Pb, colmax, colinv);
  hipLaunchKernelGGL(gemm_pv_kernel, dim3(ND_ / 128, T_ / 128, B_), dim3(256), 0, stream, Pb, Vt, out);
}

// Round 3
// 328.136 us; speedup vs baseline: 2.1206x; 1.2329x over previous
//
#include <hip/hip_runtime.h>
#include <hip/hip_bf16.h>

#define B_   8
#define T_   2048
#define EMB_ 1024
#define ND_  1024
#define NTB  16     // T_/128
#define NPAIR 136   // NTB*(NTB+1)/2

typedef __attribute__((ext_vector_type(8))) short   bf8_t;   // 8 bf16 elements (4 VGPRs)
typedef __attribute__((ext_vector_type(4))) float   f32x4;

__device__ __forceinline__ unsigned short f2bf(float f) {
  union { float f; unsigned int u; } c; c.f = f;
  unsigned int u = c.u;
  unsigned int r = (u + 0x7FFFu + ((u >> 16) & 1u)) >> 16;
  return (unsigned short)r;
}

__device__ __forceinline__ float bf2f(unsigned short b) {
  union { unsigned int u; float f; } c; c.u = ((unsigned int)b) << 16;
  return c.f;
}

__device__ __forceinline__ void gload_lds16(const unsigned short* g, unsigned short* l) {
  __builtin_amdgcn_global_load_lds(
      (const __attribute__((address_space(1))) unsigned int*)g,
      (__attribute__((address_space(3))) unsigned int*)l,
      16, 0, 0);
}

// ---------------- old 128x32 staging + mfma step (kept for scoretile / gemm_pv) -----
__device__ __forceinline__ void stage128x32(const unsigned short* __restrict__ g,
                                            int lda, unsigned short* lds,
                                            int wave, int lane) {
  const int rsub = lane >> 2;
  const int koff = (lane & 3) * 8;
#pragma unroll
  for (int c = 0; c < 2; ++c) {
    const int chunk = wave * 2 + c;
    const unsigned short* src = g + (size_t)(chunk * 16 + rsub) * lda + koff;
    gload_lds16(src, lds + chunk * 512);
  }
}

__device__ __forceinline__ void mfma_step(const unsigned short* As, const unsigned short* Bs,
                                          f32x4 acc[4][4], int lane, int wm, int wn) {
  const int r = lane & 15, k8 = (lane >> 4) * 8;
  bf8_t a[4], b[4];
#pragma unroll
  for (int m = 0; m < 4; ++m)
    a[m] = *(const bf8_t*)(As + (size_t)(wm * 64 + m * 16 + r) * 32 + k8);
#pragma unroll
  for (int n = 0; n < 4; ++n)
    b[n] = *(const bf8_t*)(Bs + (size_t)(wn * 64 + n * 16 + r) * 32 + k8);
#pragma unroll
  for (int m = 0; m < 4; ++m)
#pragma unroll
    for (int n = 0; n < 4; ++n)
      acc[m][n] = __builtin_amdgcn_mfma_f32_16x16x32_bf16(a[m], b[n], acc[m][n], 0, 0, 0);
}

__device__ __forceinline__ void zero_acc(f32x4 acc[4][4]) {
#pragma unroll
  for (int m = 0; m < 4; ++m)
#pragma unroll
    for (int n = 0; n < 4; ++n)
#pragma unroll
      for (int q = 0; q < 4; ++q) acc[m][n][q] = 0.f;
}

__device__ __forceinline__ void tri_decode(int p, int& tblk, int& sblk) {
  int t = (int)((sqrtf(8.0f * (float)p + 1.0f) - 1.0f) * 0.5f);
  while ((t + 1) * (t + 2) / 2 <= p) ++t;
  while (t * (t + 1) / 2 > p) --t;
  tblk = t;
  sblk = p - t * (t + 1) / 2;
}

// ---------------- X -> bf16 ----------------
__global__ void __launch_bounds__(256) cvt_x_kernel(const float* __restrict__ in,
                                                    unsigned short* __restrict__ out) {
  const int i = (blockIdx.x * 256 + threadIdx.x) * 4;
  float4 v = *(const float4*)(in + i);
  ushort4 o = make_ushort4(f2bf(v.x), f2bf(v.y), f2bf(v.z), f2bf(v.w));
  *(ushort4*)(out + i) = o;
}

// ---------------- W [K][N] f32 -> Wt [N][K] bf16 (optionally scaled) ----------------
__global__ void __launch_bounds__(256) transpose_w_kernel(const float* __restrict__ W,
                                                          unsigned short* __restrict__ Wt,
                                                          float cscale) {
  __shared__ unsigned short tile[32][33];
  const int n0 = blockIdx.x * 32, k0 = blockIdx.y * 32;
  const int tx = threadIdx.x & 31, ty = threadIdx.x >> 5;
#pragma unroll
  for (int r = 0; r < 32; r += 8) {
    float v = W[(size_t)(k0 + ty + r) * ND_ + n0 + tx];
    tile[tx][ty + r] = f2bf(v * cscale);
  }
  __syncthreads();
#pragma unroll
  for (int r = 0; r < 32; r += 8) {
    Wt[(size_t)(n0 + ty + r) * EMB_ + k0 + tx] = tile[ty + r][tx];
  }
}

// ================= 256x256 8-phase GEMM (T2+T3+T4+T5) =================
// A [M][K] bf16, Bt [N][K] bf16; C = A @ Bt^T.
// 512 threads = 8 waves (2 M x 4 N); per-wave output 128x64 = acc[8][4] f32x4.
// LDS 128 KiB: A/B x 2 dbuf x 2 halves of [128][64] bf16, XOR-swizzled content.

#define LDSA(d, h) (lds256 + ((d) * 2 + (h)) * 8192)
#define LDSB(d, h) (lds256 + 32768 + ((d) * 2 + (h)) * 8192)
#define SB0() __builtin_amdgcn_sched_barrier(0)
#define BAR() __builtin_amdgcn_s_barrier()

// Stage one 128x64 bf16 half-tile. Dest LDS is linear (gload_lds writes
// base+lane*16); source column is pre-XOR-swizzled so that
// lds[row][ce] == G[row][k0 + (ce ^ ((row&7)<<3))]  (rule 21: both-sides swizzle).
__device__ __forceinline__ void stage_half(const unsigned short* __restrict__ g, int lda,
                                           unsigned short* lhalf, int wave, int lane) {
  const int r3 = lane >> 3, c3 = lane & 7;
  const int colsw = ((c3 ^ r3) << 3);
#pragma unroll
  for (int j = 0; j < 2; ++j) {
    const int row = wave * 8 + r3 + 64 * j;
    gload_lds16(g + (size_t)row * lda + colsw, lhalf + wave * 512 + j * 4096);
  }
}

// Read one bf16x8 MFMA fragment at half-local row r, K-subtile ks, with swizzle undo.
__device__ __forceinline__ bf8_t read_frag(const unsigned short* half, int r, int ks, int lane) {
  const int col = (((ks) << 5) + ((lane >> 4) << 3)) ^ ((r & 7) << 3);
  return *(const bf8_t*)(half + r * 64 + col);
}

#define MFMA_QUAD(MB, AF, AOFF) do { \
  __builtin_amdgcn_s_setprio(1); \
  _Pragma("unroll") \
  for (int mi = 0; mi < 2; ++mi) \
    _Pragma("unroll") \
    for (int nf = 0; nf < 4; ++nf) \
      _Pragma("unroll") \
      for (int ks = 0; ks < 2; ++ks) \
        acc[(MB) * 2 + mi][nf] = __builtin_amdgcn_mfma_f32_16x16x32_bf16( \
            (AF)[(AOFF) + mi][ks], bfr[nf][ks], acc[(MB) * 2 + mi][nf], 0, 0, 0); \
  __builtin_amdgcn_s_setprio(0); \
} while (0)

template <int OUTMODE>
__global__ void __launch_bounds__(512, 2)
gemm_xw256_kernel(const unsigned short* __restrict__ A,
                  const unsigned short* __restrict__ Bt,
                  unsigned short* __restrict__ C) {
  extern __shared__ unsigned short lds256[];
  const int tid = threadIdx.x, lane = tid & 63, wave = tid >> 6;
  const int wm = wave >> 2, wn = wave & 3;
  const int m0 = blockIdx.y * 256, n0 = blockIdx.x * 256;
  const unsigned short* Ab = A + (size_t)m0 * EMB_;
  const unsigned short* Bb = Bt + (size_t)n0 * EMB_;

  f32x4 acc[8][4];
#pragma unroll
  for (int i = 0; i < 8; ++i)
#pragma unroll
    for (int j = 0; j < 4; ++j)
#pragma unroll
      for (int q = 0; q < 4; ++q) acc[i][j][q] = 0.f;

  const int arow = lane & 15;
  const int brow = (wn & 1) * 64 + (lane & 15);

  // Prologue: stage K-tile0 (4 halves), then B0(t1), B1(t1), A0(t1).
  stage_half(Ab,                            EMB_, LDSA(0, 0), wave, lane);
  stage_half(Ab + (size_t)128 * EMB_,       EMB_, LDSA(0, 1), wave, lane);
  stage_half(Bb,                            EMB_, LDSB(0, 0), wave, lane);
  stage_half(Bb + (size_t)128 * EMB_,       EMB_, LDSB(0, 1), wave, lane);
  stage_half(Bb + 64,                       EMB_, LDSB(1, 0), wave, lane);
  stage_half(Bb + (size_t)128 * EMB_ + 64,  EMB_, LDSB(1, 1), wave, lane);
  stage_half(Ab + 64,                       EMB_, LDSA(1, 0), wave, lane);
  asm volatile("s_waitcnt vmcnt(6)" ::: "memory");
  SB0(); BAR(); SB0();

  for (int t = 0; t < 16; ++t) {
    const int d = t & 1;
    const unsigned short* Ah = LDSA(d, wm);
    const unsigned short* Bh = LDSB(d, wn >> 1);

    // ---------- phase q0: read B + A-lo frags; stage A1(t+1); MFMA quadrant0 ----------
    bf8_t bfr[4][2], af[4][2];
#pragma unroll
    for (int nf = 0; nf < 4; ++nf)
#pragma unroll
      for (int ks = 0; ks < 2; ++ks) bfr[nf][ks] = read_frag(Bh, brow + nf * 16, ks, lane);
#pragma unroll
    for (int mf = 0; mf < 4; ++mf)
#pragma unroll
      for (int ks = 0; ks < 2; ++ks) af[mf][ks] = read_frag(Ah, arow + mf * 16, ks, lane);
    SB0();
    if (t < 15) stage_half(Ab + (size_t)128 * EMB_ + (size_t)(t + 1) * 64, EMB_, LDSA(d ^ 1, 1), wave, lane);
    SB0(); BAR(); SB0();
    MFMA_QUAD(0, af, 0);
    SB0();
    asm volatile("s_waitcnt lgkmcnt(0)" ::: "memory");
    SB0(); BAR(); SB0();

    // ---------- phase q1: stage B0(t+2); MFMA quadrant1 ----------
    if (t < 14) stage_half(Bb + (size_t)(t + 2) * 64, EMB_, LDSB(d, 0), wave, lane);
    SB0(); BAR(); SB0();
    MFMA_QUAD(1, af, 2);
    SB0(); BAR(); SB0();

    // ---------- phase q2: read A-hi frags; stage B1(t+2); MFMA quadrant2 ----------
    bf8_t af2[4][2];
#pragma unroll
    for (int mf = 0; mf < 4; ++mf)
#pragma unroll
      for (int ks = 0; ks < 2; ++ks) af2[mf][ks] = read_frag(Ah, arow + (mf + 4) * 16, ks, lane);
    SB0();
    if (t < 14) stage_half(Bb + (size_t)128 * EMB_ + (size_t)(t + 2) * 64, EMB_, LDSB(d, 1), wave, lane);
    SB0(); BAR(); SB0();
    MFMA_QUAD(2, af2, 0);
    SB0();
    asm volatile("s_waitcnt lgkmcnt(0)" ::: "memory");
    SB0(); BAR(); SB0();

    // ---------- phase q3: stage A0(t+2); counted vmcnt; MFMA quadrant3 ----------
    if (t < 14) stage_half(Ab + (size_t)(t + 2) * 64, EMB_, LDSA(d, 0), wave, lane);
    if (t < 14)      { asm volatile("s_waitcnt vmcnt(6)" ::: "memory"); }
    else if (t == 14){ asm volatile("s_waitcnt vmcnt(0)" ::: "memory"); }
    SB0(); BAR(); SB0();
    MFMA_QUAD(3, af2, 2);
    SB0(); BAR(); SB0();
  }

  // Epilogue
  const int cc = lane & 15, cr4 = (lane >> 4) << 2;
#pragma unroll
  for (int mf = 0; mf < 8; ++mf)
#pragma unroll
    for (int nf = 0; nf < 4; ++nf)
#pragma unroll
      for (int q = 0; q < 4; ++q) {
        const int row = m0 + wm * 128 + mf * 16 + cr4 + q;
        const int col = n0 + wn * 64 + nf * 16 + cc;
        const unsigned short val = f2bf(acc[mf][nf][q]);
        if (OUTMODE == 0) {
          C[(size_t)row * ND_ + col] = val;
        } else {
          const int bb = row >> 11, tt = row & 2047;
          C[((size_t)bb * ND_ + col) * T_ + tt] = val;
        }
      }
}

// ---------------- S tiles (lower triangle, packed grid) + column partial stats -------
__global__ void __launch_bounds__(256) scoretile_kernel(const unsigned short* __restrict__ Qb,
                                                        const unsigned short* __restrict__ Kb,
                                                        unsigned short* __restrict__ Sb,
                                                        float* __restrict__ pm,
                                                        float* __restrict__ pl) {
  int tblk, sblk;
  tri_decode(blockIdx.x, tblk, sblk);
  const int b = blockIdx.y;
  __shared__ unsigned short As[128 * 32], Bs[128 * 32];
  __shared__ float redm[2][2][4][16], redl[2][2][4][16];
  const int tid = threadIdx.x, lane = tid & 63, wave = tid >> 6;
  const int wm = wave >> 1, wn = wave & 1;
  const int t0 = tblk * 128, s0 = sblk * 128;
  const unsigned short* Qbase = Qb + ((size_t)b * T_ + t0) * ND_;
  const unsigned short* Kbase = Kb + ((size_t)b * T_ + s0) * ND_;
  f32x4 acc[4][4];
  zero_acc(acc);
  for (int k = 0; k < ND_; k += 32) {
    __syncthreads();
    stage128x32(Qbase + k, ND_, As, wave, lane);
    stage128x32(Kbase + k, ND_, Bs, wave, lane);
    __syncthreads();
    mfma_step(As, Bs, acc, lane, wm, wn);
  }
  const int cr = ((lane >> 4) << 2), cc = lane & 15;
  unsigned short* Pbase = Sb + (size_t)b * T_ * T_;
  const bool diag = (tblk == sblk);
  float rm[4], rl[4];
#pragma unroll
  for (int n = 0; n < 4; ++n) { rm[n] = -1e30f; rl[n] = 0.f; }
#pragma unroll
  for (int n = 0; n < 4; ++n) {
    const int s = s0 + wn * 64 + n * 16 + cc;
#pragma unroll
    for (int m = 0; m < 4; ++m)
#pragma unroll
      for (int q = 0; q < 4; ++q) {
        const int t = t0 + wm * 64 + m * 16 + cr + q;
        if (!diag || t >= s) {
          const unsigned short bv = f2bf(acc[m][n][q]);
          Pbase[(size_t)t * T_ + s] = bv;
          const float v = bf2f(bv);
          const float mm = fmaxf(rm[n], v);
          rl[n] = rl[n] * __expf(rm[n] - mm) + __expf(v - mm);
          rm[n] = mm;
        }
      }
  }
#pragma unroll
  for (int n = 0; n < 4; ++n) {
#pragma unroll
    for (int off = 16; off < 64; off <<= 1) {
      const float om = __shfl_xor(rm[n], off);
      const float ol = __shfl_xor(rl[n], off);
      const float mm = fmaxf(rm[n], om);
      rl[n] = rl[n] * __expf(rm[n] - mm) + ol * __expf(om - mm);
      rm[n] = mm;
    }
  }
  __syncthreads();
  if (lane < 16) {
#pragma unroll
    for (int n = 0; n < 4; ++n) { redm[wm][wn][n][lane] = rm[n]; redl[wm][wn][n][lane] = rl[n]; }
  }
  __syncthreads();
  if (wm == 0 && lane < 16) {
    const size_t base = (((size_t)b * NTB + sblk) * NTB + tblk) * 128;
#pragma unroll
    for (int n = 0; n < 4; ++n) {
      const float m0v = redm[0][wn][n][lane], l0v = redl[0][wn][n][lane];
      const float m1v = redm[1][wn][n][lane], l1v = redl[1][wn][n][lane];
      const float mm = fmaxf(m0v, m1v);
      const float ll = l0v * __expf(m0v - mm) + l1v * __expf(m1v - mm);
      pm[base + wn * 64 + n * 16 + lane] = mm;
      pl[base + wn * 64 + n * 16 + lane] = ll;
    }
  }
}

// ---------------- fold per-tile partials into colmax / colinv ----------------
__global__ void __launch_bounds__(128) colreduce_kernel(const float* __restrict__ pm,
                                                        const float* __restrict__ pl,
                                                        float* __restrict__ colmax,
                                                        float* __restrict__ colinv) {
  const int sblk = blockIdx.x, b = blockIdx.y, c = threadIdx.x;
  float m = -1e30f, l = 0.f;
  for (int tblk = sblk; tblk < NTB; ++tblk) {
    const size_t base = (((size_t)b * NTB + sblk) * NTB + tblk) * 128;
    const float om = pm[base + c], ol = pl[base + c];
    const float mm = fmaxf(m, om);
    l = l * __expf(m - mm) + ol * __expf(om - mm);
    m = mm;
  }
  colmax[(size_t)b * T_ + sblk * 128 + c] = m;
  colinv[(size_t)b * T_ + sblk * 128 + c] = 1.0f / l;
}

// ---------------- P = exp(S - m_s) * inv_l_s, in place (packed grid) ----------------
__global__ void __launch_bounds__(256) pscale_kernel(unsigned short* __restrict__ Pb,
                                                     const float* __restrict__ colmax,
                                                     const float* __restrict__ colinv) {
  int tblk, sblk;
  tri_decode(blockIdx.x, tblk, sblk);
  const int b = blockIdx.y;
  const int s0 = sblk * 128, t0 = tblk * 128;
  const int tid = threadIdx.x;
  const int col8 = (tid & 15) * 8;
  const int rbase = tid >> 4;
  unsigned short* Pbase = Pb + (size_t)b * T_ * T_;
  float ms[8], inv[8];
#pragma unroll
  for (int j = 0; j < 8; ++j) {
    ms[j]  = colmax[(size_t)b * T_ + s0 + col8 + j];
    inv[j] = colinv[(size_t)b * T_ + s0 + col8 + j];
  }
  const bool diag = (tblk == sblk);
  for (int r = rbase; r < 128; r += 16) {
    const int t = t0 + r;
    unsigned short* p = Pbase + (size_t)t * T_ + s0 + col8;
    bf8_t v = *(bf8_t*)p;
#pragma unroll
    for (int j = 0; j < 8; ++j) {
      float pv = 0.f;
      if (!diag || t >= s0 + col8 + j) {
        pv = __expf(bf2f((unsigned short)v[j]) - ms[j]) * inv[j];
      }
      v[j] = (short)f2bf(pv);
    }
    *(bf8_t*)p = v;
  }
}

// ---------------- out = P @ V  (A = Pb [T][T] bf16, Bt = Vt [ND][T] bf16, C f32) -----
__global__ void __launch_bounds__(256) gemm_pv_kernel(const unsigned short* __restrict__ Pb,
                                                      const unsigned short* __restrict__ Vt,
                                                      float* __restrict__ out) {
  __shared__ unsigned short As[128 * 32], Bs[128 * 32];
  const int nblk = blockIdx.x, tblk = blockIdx.y, b = blockIdx.z;
  const int tid = threadIdx.x, lane = tid & 63, wave = tid >> 6;
  const int wm = wave >> 1, wn = wave & 1;
  const int m0 = tblk * 128, n0 = nblk * 128;
  const unsigned short* Ab = Pb + (size_t)b * T_ * T_ + (size_t)m0 * T_;
  const unsigned short* Bb = Vt + (size_t)b * ND_ * T_ + (size_t)n0 * T_;
  f32x4 acc[4][4];
  zero_acc(acc);
  const int kmax = m0 + 128;
  for (int k = 0; k < kmax; k += 32) {
    __syncthreads();
    stage128x32(Ab + k, T_, As, wave, lane);
    stage128x32(Bb + k, T_, Bs, wave, lane);
    __syncthreads();
    mfma_step(As, Bs, acc, lane, wm, wn);
  }
  float* Cb = out + (size_t)b * T_ * ND_;
  const int cr = ((lane >> 4) << 2), cc = lane & 15;
#pragma unroll
  for (int m = 0; m < 4; ++m)
#pragma unroll
    for (int n = 0; n < 4; ++n)
#pragma unroll
      for (int q = 0; q < 4; ++q) {
        const int row = m0 + wm * 64 + m * 16 + cr + q;
        const int col = n0 + wn * 64 + n * 16 + cc;
        Cb[(size_t)row * ND_ + col] = acc[m][n][q];
      }
}

extern "C" void kernel_launch(void* const* d_in, const int* in_sizes, int n_in,
                              void* d_out, int out_size, void* d_ws, size_t ws_size,
                              hipStream_t stream) {
  const float* X  = (const float*)d_in[0];
  const float* Wq = (const float*)d_in[1];
  const float* Wk = (const float*)d_in[2];
  const float* Wv = (const float*)d_in[3];
  float* out = (float*)d_out;
  (void)in_sizes; (void)n_in; (void)out_size;

  char* ws = (char*)d_ws;
  size_t off = 0;
  auto alloc = [&](size_t bytes) {
    void* p = ws + off;
    off += (bytes + 255) & ~(size_t)255;
    return p;
  };
  unsigned short* Xb  = (unsigned short*)alloc((size_t)B_ * T_ * EMB_ * 2);
  unsigned short* Wtq = (unsigned short*)alloc((size_t)ND_ * EMB_ * 2);
  unsigned short* Wtk = (unsigned short*)alloc((size_t)ND_ * EMB_ * 2);
  unsigned short* Wtv = (unsigned short*)alloc((size_t)ND_ * EMB_ * 2);
  unsigned short* Qb  = (unsigned short*)alloc((size_t)B_ * T_ * ND_ * 2);
  unsigned short* Kb  = (unsigned short*)alloc((size_t)B_ * T_ * ND_ * 2);
  unsigned short* Vt  = (unsigned short*)alloc((size_t)B_ * ND_ * T_ * 2);
  float* colmax = (float*)alloc((size_t)B_ * T_ * 4);
  float* colinv = (float*)alloc((size_t)B_ * T_ * 4);
  float* pm     = (float*)alloc((size_t)B_ * NTB * NTB * 128 * 4);
  float* pl     = (float*)alloc((size_t)B_ * NTB * NTB * 128 * 4);
  unsigned short* Pb  = (unsigned short*)alloc((size_t)B_ * T_ * T_ * 2);
  if (off > ws_size) return;

  hipFuncSetAttribute((const void*)&gemm_xw256_kernel<0>,
                      hipFuncAttributeMaxDynamicSharedMemorySize, 131072);
  hipFuncSetAttribute((const void*)&gemm_xw256_kernel<1>,
                      hipFuncAttributeMaxDynamicSharedMemorySize, 131072);

  hipLaunchKernelGGL(cvt_x_kernel, dim3((B_ * T_ * EMB_) / 1024), dim3(256), 0, stream, X, Xb);
  hipLaunchKernelGGL(transpose_w_kernel, dim3(32, 32), dim3(256), 0, stream, Wq, Wtq, 0.03125f);
  hipLaunchKernelGGL(transpose_w_kernel, dim3(32, 32), dim3(256), 0, stream, Wk, Wtk, 1.0f);
  hipLaunchKernelGGL(transpose_w_kernel, dim3(32, 32), dim3(256), 0, stream, Wv, Wtv, 1.0f);
  hipLaunchKernelGGL((gemm_xw256_kernel<0>), dim3(ND_ / 256, (B_ * T_) / 256), dim3(512), 131072, stream, Xb, Wtq, Qb);
  hipLaunchKernelGGL((gemm_xw256_kernel<0>), dim3(ND_ / 256, (B_ * T_) / 256), dim3(512), 131072, stream, Xb, Wtk, Kb);
  hipLaunchKernelGGL((gemm_xw256_kernel<1>), dim3(ND_ / 256, (B_ * T_) / 256), dim3(512), 131072, stream, Xb, Wtv, Vt);
  hipLaunchKernelGGL(scoretile_kernel, dim3(NPAIR, B_), dim3(256), 0, stream, Qb, Kb, Pb, pm, pl);
  hipLaunchKernelGGL(colreduce_kernel, dim3(NTB, B_), dim3(128), 0, stream, pm, pl, colmax, colinv);
  hipLaunchKernelGGL(pscale_kernel, dim3(NPAIR, B_), dim3(256), 0, stream, Pb, colmax, colinv);
  hipLaunchKernelGGL(gemm_pv_kernel, dim3(ND_ / 128, T_ / 128, B_), dim3(256), 0, stream, Pb, Vt, out);
}

// Round 4
// 305.207 us; speedup vs baseline: 2.2799x; 1.0751x over previous
//
#include <hip/hip_runtime.h>
#include <hip/hip_bf16.h>

#define B_   8
#define T_   2048
#define EMB_ 1024
#define ND_  1024
#define NTB  16     // T_/128
#define NPAIR 136   // 128-granularity lower-tri pairs
#define NTB2 8      // T_/256
#define NPAIR2 36   // 256-granularity lower-tri pairs

typedef __attribute__((ext_vector_type(8))) short   bf8_t;   // 8 bf16 elements (4 VGPRs)
typedef __attribute__((ext_vector_type(4))) float   f32x4;

__device__ __forceinline__ unsigned short f2bf(float f) {
  union { float f; unsigned int u; } c; c.f = f;
  unsigned int u = c.u;
  unsigned int r = (u + 0x7FFFu + ((u >> 16) & 1u)) >> 16;
  return (unsigned short)r;
}

__device__ __forceinline__ float bf2f(unsigned short b) {
  union { unsigned int u; float f; } c; c.u = ((unsigned int)b) << 16;
  return c.f;
}

__device__ __forceinline__ void gload_lds16(const unsigned short* g, unsigned short* l) {
  __builtin_amdgcn_global_load_lds(
      (const __attribute__((address_space(1))) unsigned int*)g,
      (__attribute__((address_space(3))) unsigned int*)l,
      16, 0, 0);
}

__device__ __forceinline__ void tri_decode(int p, int& tblk, int& sblk) {
  int t = (int)((sqrtf(8.0f * (float)p + 1.0f) - 1.0f) * 0.5f);
  while ((t + 1) * (t + 2) / 2 <= p) ++t;
  while (t * (t + 1) / 2 > p) --t;
  tblk = t;
  sblk = p - t * (t + 1) / 2;
}

#define SB0() __builtin_amdgcn_sched_barrier(0)
#define BAR() __builtin_amdgcn_s_barrier()

// Stage one 128x64 bf16 half-tile. Dest LDS is linear; source column is
// pre-XOR-swizzled so lds[row][ce] == G[row][k0 + (ce ^ ((row&7)<<3))].
__device__ __forceinline__ void stage_half(const unsigned short* __restrict__ g, int lda,
                                           unsigned short* lhalf, int wave, int lane) {
  const int r3 = lane >> 3, c3 = lane & 7;
  const int colsw = ((c3 ^ r3) << 3);
#pragma unroll
  for (int j = 0; j < 2; ++j) {
    const int row = wave * 8 + r3 + 64 * j;
    gload_lds16(g + (size_t)row * lda + colsw, lhalf + wave * 512 + j * 4096);
  }
}

// Read one bf16x8 MFMA fragment at half-local row r, K-subtile ks, undoing swizzle.
__device__ __forceinline__ bf8_t read_frag(const unsigned short* half, int r, int ks, int lane) {
  const int col = (((ks) << 5) + ((lane >> 4) << 3)) ^ ((r & 7) << 3);
  return *(const bf8_t*)(half + r * 64 + col);
}

// ---------------- X -> bf16 ----------------
__global__ void __launch_bounds__(256) cvt_x_kernel(const float* __restrict__ in,
                                                    unsigned short* __restrict__ out) {
  const int i = (blockIdx.x * 256 + threadIdx.x) * 4;
  float4 v = *(const float4*)(in + i);
  ushort4 o = make_ushort4(f2bf(v.x), f2bf(v.y), f2bf(v.z), f2bf(v.w));
  *(ushort4*)(out + i) = o;
}

// ---------------- W [K][N] f32 -> Wt [N][K] bf16 (optionally scaled) ----------------
__global__ void __launch_bounds__(256) transpose_w_kernel(const float* __restrict__ W,
                                                          unsigned short* __restrict__ Wt,
                                                          float cscale) {
  __shared__ unsigned short tile[32][33];
  const int n0 = blockIdx.x * 32, k0 = blockIdx.y * 32;
  const int tx = threadIdx.x & 31, ty = threadIdx.x >> 5;
#pragma unroll
  for (int r = 0; r < 32; r += 8) {
    float v = W[(size_t)(k0 + ty + r) * ND_ + n0 + tx];
    tile[tx][ty + r] = f2bf(v * cscale);
  }
  __syncthreads();
#pragma unroll
  for (int r = 0; r < 32; r += 8) {
    Wt[(size_t)(n0 + ty + r) * EMB_ + k0 + tx] = tile[ty + r][tx];
  }
}

// ================= 256x256 8-phase core (4 halves per K-tile) =================
#define LDSA(d, h) (lds256 + ((d) * 2 + (h)) * 8192)
#define LDSB(d, h) (lds256 + 32768 + ((d) * 2 + (h)) * 8192)

#define MFMA_QUAD(MB, AF, AOFF) do { \
  __builtin_amdgcn_s_setprio(1); \
  _Pragma("unroll") \
  for (int mi = 0; mi < 2; ++mi) \
    _Pragma("unroll") \
    for (int nf = 0; nf < 4; ++nf) \
      _Pragma("unroll") \
      for (int ks = 0; ks < 2; ++ks) \
        acc[(MB) * 2 + mi][nf] = __builtin_amdgcn_mfma_f32_16x16x32_bf16( \
            (AF)[(AOFF) + mi][ks], bfr[nf][ks], acc[(MB) * 2 + mi][nf], 0, 0, 0); \
  __builtin_amdgcn_s_setprio(0); \
} while (0)

// Main 16-K-tile 256x256 loop; acc must be zeroed by caller. lda==ldb==1024.
#define GEMM256_LOOP(ABASE, BBASE, LDK) \
  stage_half((ABASE),                           (LDK), LDSA(0, 0), wave, lane); \
  stage_half((ABASE) + (size_t)128 * (LDK),     (LDK), LDSA(0, 1), wave, lane); \
  stage_half((BBASE),                           (LDK), LDSB(0, 0), wave, lane); \
  stage_half((BBASE) + (size_t)128 * (LDK),     (LDK), LDSB(0, 1), wave, lane); \
  stage_half((BBASE) + 64,                      (LDK), LDSB(1, 0), wave, lane); \
  stage_half((BBASE) + (size_t)128 * (LDK) + 64,(LDK), LDSB(1, 1), wave, lane); \
  stage_half((ABASE) + 64,                      (LDK), LDSA(1, 0), wave, lane); \
  asm volatile("s_waitcnt vmcnt(6)" ::: "memory"); \
  SB0(); BAR(); SB0(); \
  for (int t = 0; t < 16; ++t) { \
    const int d = t & 1; \
    const unsigned short* Ah = LDSA(d, wm); \
    const unsigned short* Bh = LDSB(d, wn >> 1); \
    bf8_t bfr[4][2], af[4][2]; \
    _Pragma("unroll") \
    for (int nf = 0; nf < 4; ++nf) \
      _Pragma("unroll") \
      for (int ks = 0; ks < 2; ++ks) bfr[nf][ks] = read_frag(Bh, brow + nf * 16, ks, lane); \
    _Pragma("unroll") \
    for (int mf = 0; mf < 4; ++mf) \
      _Pragma("unroll") \
      for (int ks = 0; ks < 2; ++ks) af[mf][ks] = read_frag(Ah, arow + mf * 16, ks, lane); \
    SB0(); \
    if (t < 15) stage_half((ABASE) + (size_t)128 * (LDK) + (size_t)(t + 1) * 64, (LDK), LDSA(d ^ 1, 1), wave, lane); \
    SB0(); BAR(); SB0(); \
    MFMA_QUAD(0, af, 0); \
    SB0(); \
    asm volatile("s_waitcnt lgkmcnt(0)" ::: "memory"); \
    SB0(); BAR(); SB0(); \
    if (t < 14) stage_half((BBASE) + (size_t)(t + 2) * 64, (LDK), LDSB(d, 0), wave, lane); \
    SB0(); BAR(); SB0(); \
    MFMA_QUAD(1, af, 2); \
    SB0(); BAR(); SB0(); \
    bf8_t af2[4][2]; \
    _Pragma("unroll") \
    for (int mf = 0; mf < 4; ++mf) \
      _Pragma("unroll") \
      for (int ks = 0; ks < 2; ++ks) af2[mf][ks] = read_frag(Ah, arow + (mf + 4) * 16, ks, lane); \
    SB0(); \
    if (t < 14) stage_half((BBASE) + (size_t)128 * (LDK) + (size_t)(t + 2) * 64, (LDK), LDSB(d, 1), wave, lane); \
    SB0(); BAR(); SB0(); \
    MFMA_QUAD(2, af2, 0); \
    SB0(); \
    asm volatile("s_waitcnt lgkmcnt(0)" ::: "memory"); \
    SB0(); BAR(); SB0(); \
    if (t < 14) stage_half((ABASE) + (size_t)(t + 2) * 64, (LDK), LDSA(d, 0), wave, lane); \
    if (t < 14)      { asm volatile("s_waitcnt vmcnt(6)" ::: "memory"); } \
    else if (t == 14){ asm volatile("s_waitcnt vmcnt(0)" ::: "memory"); } \
    SB0(); BAR(); SB0(); \
    MFMA_QUAD(3, af2, 2); \
    SB0(); BAR(); SB0(); \
  }

template <int OUTMODE>
__global__ void __launch_bounds__(512, 2)
gemm_xw256_kernel(const unsigned short* __restrict__ A,
                  const unsigned short* __restrict__ Bt,
                  unsigned short* __restrict__ C) {
  extern __shared__ unsigned short lds256[];
  const int tid = threadIdx.x, lane = tid & 63, wave = tid >> 6;
  const int wm = wave >> 2, wn = wave & 3;
  const int m0 = blockIdx.y * 256, n0 = blockIdx.x * 256;
  const unsigned short* Ab = A + (size_t)m0 * EMB_;
  const unsigned short* Bb = Bt + (size_t)n0 * EMB_;
  f32x4 acc[8][4];
#pragma unroll
  for (int i = 0; i < 8; ++i)
#pragma unroll
    for (int j = 0; j < 4; ++j)
#pragma unroll
      for (int q = 0; q < 4; ++q) acc[i][j][q] = 0.f;
  const int arow = lane & 15;
  const int brow = (wn & 1) * 64 + (lane & 15);

  GEMM256_LOOP(Ab, Bb, EMB_)

  const int cc = lane & 15, cr4 = (lane >> 4) << 2;
#pragma unroll
  for (int mf = 0; mf < 8; ++mf)
#pragma unroll
    for (int nf = 0; nf < 4; ++nf)
#pragma unroll
      for (int q = 0; q < 4; ++q) {
        const int row = m0 + wm * 128 + mf * 16 + cr4 + q;
        const int col = n0 + wn * 64 + nf * 16 + cc;
        const unsigned short val = f2bf(acc[mf][nf][q]);
        if (OUTMODE == 0) {
          C[(size_t)row * ND_ + col] = val;
        } else {
          const int bb = row >> 11, tt = row & 2047;
          C[((size_t)bb * ND_ + col) * T_ + tt] = val;
        }
      }
}

// --------- S tiles at 256 granularity + column partial stats (8-phase core) ---------
__global__ void __launch_bounds__(512, 2)
scoretile256_kernel(const unsigned short* __restrict__ Qb,
                    const unsigned short* __restrict__ Kb,
                    unsigned short* __restrict__ Sb,
                    float* __restrict__ pm,
                    float* __restrict__ pl) {
  extern __shared__ unsigned short lds256[];
  int tr, sr;
  tri_decode(blockIdx.x, tr, sr);
  const int b = blockIdx.y;
  const int tid = threadIdx.x, lane = tid & 63, wave = tid >> 6;
  const int wm = wave >> 2, wn = wave & 3;
  const int t0 = tr * 256, s0 = sr * 256;
  const unsigned short* Ab = Qb + ((size_t)b * T_ + t0) * ND_;
  const unsigned short* Bb = Kb + ((size_t)b * T_ + s0) * ND_;
  f32x4 acc[8][4];
#pragma unroll
  for (int i = 0; i < 8; ++i)
#pragma unroll
    for (int j = 0; j < 4; ++j)
#pragma unroll
      for (int q = 0; q < 4; ++q) acc[i][j][q] = 0.f;
  const int arow = lane & 15;
  const int brow = (wn & 1) * 64 + (lane & 15);

  GEMM256_LOOP(Ab, Bb, ND_)

  // ---- epilogue: masked S write + column stats ----
  const int cc = lane & 15, cr4 = (lane >> 4) << 2;
  const bool diag = (tr == sr);
  unsigned short* Sbase = Sb + (size_t)b * T_ * T_;
  float rm[4], rl[4];
#pragma unroll
  for (int nf = 0; nf < 4; ++nf) { rm[nf] = -1e30f; rl[nf] = 0.f; }
#pragma unroll
  for (int mf = 0; mf < 8; ++mf)
#pragma unroll
    for (int nf = 0; nf < 4; ++nf)
#pragma unroll
      for (int q = 0; q < 4; ++q) {
        const int t = t0 + wm * 128 + mf * 16 + cr4 + q;
        const int s = s0 + wn * 64 + nf * 16 + cc;
        const bool ok = !diag || (t >= s);
        const unsigned short bv = ok ? f2bf(acc[mf][nf][q]) : (unsigned short)0;
        Sbase[(size_t)t * T_ + s] = bv;
        if (ok) {
          const float v = bf2f(bv);
          const float mm = fmaxf(rm[nf], v);
          rl[nf] = rl[nf] * __expf(rm[nf] - mm) + __expf(v - mm);
          rm[nf] = mm;
        }
      }
#pragma unroll
  for (int nf = 0; nf < 4; ++nf) {
#pragma unroll
    for (int off = 16; off < 64; off <<= 1) {
      const float om = __shfl_xor(rm[nf], off);
      const float ol = __shfl_xor(rl[nf], off);
      const float mm = fmaxf(rm[nf], om);
      rl[nf] = rl[nf] * __expf(rm[nf] - mm) + ol * __expf(om - mm);
      rm[nf] = mm;
    }
  }
  __syncthreads();              // main-loop LDS traffic fully drained
  float* red = (float*)lds256;  // [2 wm][4 wn][4 nf][16] x2
  if (lane < 16) {
#pragma unroll
    for (int nf = 0; nf < 4; ++nf) {
      red[((wm * 4 + wn) * 4 + nf) * 16 + lane] = rm[nf];
      red[512 + ((wm * 4 + wn) * 4 + nf) * 16 + lane] = rl[nf];
    }
  }
  __syncthreads();
  if (wm == 0 && lane < 16) {
    const size_t base = (((size_t)b * NTB2 + sr) * NTB2 + tr) * 256;
#pragma unroll
    for (int nf = 0; nf < 4; ++nf) {
      const float m0v = red[((0 * 4 + wn) * 4 + nf) * 16 + lane];
      const float l0v = red[512 + ((0 * 4 + wn) * 4 + nf) * 16 + lane];
      const float m1v = red[((1 * 4 + wn) * 4 + nf) * 16 + lane];
      const float l1v = red[512 + ((1 * 4 + wn) * 4 + nf) * 16 + lane];
      const float mm = fmaxf(m0v, m1v);
      const float ll = l0v * __expf(m0v - mm) + l1v * __expf(m1v - mm);
      pm[base + wn * 64 + nf * 16 + lane] = mm;
      pl[base + wn * 64 + nf * 16 + lane] = ll;
    }
  }
}

// ---------------- fold per-tile partials into colmax / colinv ----------------
__global__ void __launch_bounds__(256) colreduce_kernel(const float* __restrict__ pm,
                                                        const float* __restrict__ pl,
                                                        float* __restrict__ colmax,
                                                        float* __restrict__ colinv) {
  const int sr = blockIdx.x, b = blockIdx.y, c = threadIdx.x;
  float m = -1e30f, l = 0.f;
  for (int tr = sr; tr < NTB2; ++tr) {
    const size_t base = (((size_t)b * NTB2 + sr) * NTB2 + tr) * 256;
    const float om = pm[base + c], ol = pl[base + c];
    const float mm = fmaxf(m, om);
    l = l * __expf(m - mm) + ol * __expf(om - mm);
    m = mm;
  }
  colmax[(size_t)b * T_ + sr * 256 + c] = m;
  colinv[(size_t)b * T_ + sr * 256 + c] = 1.0f / l;
}

// ---------------- P = exp(S - m_s) * inv_l_s, in place (128-granularity) ----------------
__global__ void __launch_bounds__(256) pscale_kernel(unsigned short* __restrict__ Pb,
                                                     const float* __restrict__ colmax,
                                                     const float* __restrict__ colinv) {
  int tblk, sblk;
  tri_decode(blockIdx.x, tblk, sblk);
  const int b = blockIdx.y;
  const int s0 = sblk * 128, t0 = tblk * 128;
  const int tid = threadIdx.x;
  const int col8 = (tid & 15) * 8;
  const int rbase = tid >> 4;
  unsigned short* Pbase = Pb + (size_t)b * T_ * T_;
  float ms[8], inv[8];
#pragma unroll
  for (int j = 0; j < 8; ++j) {
    ms[j]  = colmax[(size_t)b * T_ + s0 + col8 + j];
    inv[j] = colinv[(size_t)b * T_ + s0 + col8 + j];
  }
  const bool diag = (tblk == sblk);
  for (int r = rbase; r < 128; r += 16) {
    const int t = t0 + r;
    unsigned short* p = Pbase + (size_t)t * T_ + s0 + col8;
    bf8_t v = *(bf8_t*)p;
#pragma unroll
    for (int j = 0; j < 8; ++j) {
      float pv = 0.f;
      if (!diag || t >= s0 + col8 + j) {
        pv = __expf(bf2f((unsigned short)v[j]) - ms[j]) * inv[j];
      }
      v[j] = (short)f2bf(pv);
    }
    *(bf8_t*)p = v;
  }
}

// ========== PV: BM=128 x BN=256, 3 halves per K-tile, triangular K, paired tiles ==========
// A half at lds[d*8192], B halves at lds[16384 + (d*2+h)*8192]; 96 KiB total.
#define MFMA_Q8(MB) do { \
  __builtin_amdgcn_s_setprio(1); \
  _Pragma("unroll") \
  for (int nf = 0; nf < 4; ++nf) \
    _Pragma("unroll") \
    for (int ks = 0; ks < 2; ++ks) \
      acc[(MB)][nf] = __builtin_amdgcn_mfma_f32_16x16x32_bf16( \
          af[(MB)][ks], bfr[nf][ks], acc[(MB)][nf], 0, 0, 0); \
  __builtin_amdgcn_s_setprio(0); \
} while (0)

__device__ __forceinline__ void pv_segment(const unsigned short* __restrict__ Ab,
                                           const unsigned short* __restrict__ Bb,
                                           float* __restrict__ Cb,
                                           int ktiles, unsigned short* lds256,
                                           int lane, int wave) {
  const int wm = wave >> 2, wn = wave & 3;  // wm: t-half (0..1), wn: d-quarter (0..3)
  const int arow = lane & 15;
  f32x4 acc[4][4];
#pragma unroll
  for (int i = 0; i < 4; ++i)
#pragma unroll
    for (int j = 0; j < 4; ++j)
#pragma unroll
      for (int q = 0; q < 4; ++q) acc[i][j][q] = 0.f;

  // Prologue: tiles 0 and 1 (3 halves each).
  stage_half(Ab,                           T_, lds256,                     wave, lane);
  stage_half(Bb,                           T_, lds256 + 16384,             wave, lane);
  stage_half(Bb + (size_t)128 * T_,        T_, lds256 + 16384 + 8192,      wave, lane);
  stage_half(Ab + 64,                      T_, lds256 + 8192,              wave, lane);
  stage_half(Bb + 64,                      T_, lds256 + 16384 + 2 * 8192,  wave, lane);
  stage_half(Bb + (size_t)128 * T_ + 64,   T_, lds256 + 16384 + 3 * 8192,  wave, lane);
  asm volatile("s_waitcnt vmcnt(6)" ::: "memory");
  SB0(); BAR(); SB0();

  for (int t = 0; t < ktiles; ++t) {
    const int d = t & 1;
    const unsigned short* Ah = lds256 + d * 8192;
    const unsigned short* Bh = lds256 + 16384 + (d * 2 + (wn >> 1)) * 8192;
    // q0: all 16 frag reads from buf d
    bf8_t bfr[4][2], af[4][2];
#pragma unroll
    for (int nf = 0; nf < 4; ++nf)
#pragma unroll
      for (int ks = 0; ks < 2; ++ks)
        bfr[nf][ks] = read_frag(Bh, (wn & 1) * 64 + nf * 16 + arow, ks, lane);
#pragma unroll
    for (int mf = 0; mf < 4; ++mf)
#pragma unroll
      for (int ks = 0; ks < 2; ++ks)
        af[mf][ks] = read_frag(Ah, wm * 64 + mf * 16 + arow, ks, lane);
    SB0(); BAR(); SB0();
    MFMA_Q8(0);
    SB0();
    asm volatile("s_waitcnt lgkmcnt(0)" ::: "memory");
    SB0(); BAR(); SB0();
    // q1: stage A(t+2) into buf d (reads of buf d all completed at q0)
    if (t < ktiles - 2) stage_half(Ab + (size_t)(t + 2) * 64, T_, lds256 + d * 8192, wave, lane);
    SB0(); BAR(); SB0();
    MFMA_Q8(1);
    SB0(); BAR(); SB0();
    // q2: stage B0(t+2)
    if (t < ktiles - 2) stage_half(Bb + (size_t)(t + 2) * 64, T_, lds256 + 16384 + (d * 2) * 8192, wave, lane);
    SB0(); BAR(); SB0();
    MFMA_Q8(2);
    SB0(); BAR(); SB0();
    // q3: stage B1(t+2); counted vmcnt
    if (t < ktiles - 2) stage_half(Bb + (size_t)128 * T_ + (size_t)(t + 2) * 64, T_, lds256 + 16384 + (d * 2 + 1) * 8192, wave, lane);
    if (t < ktiles - 2)      { asm volatile("s_waitcnt vmcnt(6)" ::: "memory"); }
    else if (t == ktiles - 2){ asm volatile("s_waitcnt vmcnt(0)" ::: "memory"); }
    SB0(); BAR(); SB0();
    MFMA_Q8(3);
    SB0(); BAR(); SB0();
  }

  const int cc = lane & 15, cr4 = (lane >> 4) << 2;
#pragma unroll
  for (int mf = 0; mf < 4; ++mf)
#pragma unroll
    for (int nf = 0; nf < 4; ++nf)
#pragma unroll
      for (int q = 0; q < 4; ++q) {
        const int row = wm * 64 + mf * 16 + cr4 + q;
        const int col = wn * 64 + nf * 16 + cc;
        Cb[(size_t)row * ND_ + col] = acc[mf][nf][q];
      }
}

// Paired triangular PV: block handles t-blocks {pair, 15-pair} -> 34 K-tiles each.
__global__ void __launch_bounds__(512, 2)
gemm_pv256_kernel(const unsigned short* __restrict__ Pb,
                  const unsigned short* __restrict__ Vt,
                  float* __restrict__ out) {
  extern __shared__ unsigned short lds256[];
  const int pair = blockIdx.x;   // 0..7
  const int ncol = blockIdx.y;   // 0..3
  const int b = blockIdx.z;
  const int tid = threadIdx.x, lane = tid & 63, wave = tid >> 6;
  const int tbs[2] = {pair, 15 - pair};
#pragma unroll
  for (int si = 0; si < 2; ++si) {
    const int tb = tbs[si];
    const int ktiles = 2 * tb + 2;
    pv_segment(Pb + (size_t)b * T_ * T_ + (size_t)tb * 128 * T_,
               Vt + (size_t)b * ND_ * T_ + (size_t)ncol * 256 * T_,
               out + (size_t)b * T_ * ND_ + (size_t)tb * 128 * ND_ + ncol * 256,
               ktiles, lds256, lane, wave);
  }
}

extern "C" void kernel_launch(void* const* d_in, const int* in_sizes, int n_in,
                              void* d_out, int out_size, void* d_ws, size_t ws_size,
                              hipStream_t stream) {
  const float* X  = (const float*)d_in[0];
  const float* Wq = (const float*)d_in[1];
  const float* Wk = (const float*)d_in[2];
  const float* Wv = (const float*)d_in[3];
  float* out = (float*)d_out;
  (void)in_sizes; (void)n_in; (void)out_size;

  char* ws = (char*)d_ws;
  size_t off = 0;
  auto alloc = [&](size_t bytes) {
    void* p = ws + off;
    off += (bytes + 255) & ~(size_t)255;
    return p;
  };
  unsigned short* Xb  = (unsigned short*)alloc((size_t)B_ * T_ * EMB_ * 2);
  unsigned short* Wtq = (unsigned short*)alloc((size_t)ND_ * EMB_ * 2);
  unsigned short* Wtk = (unsigned short*)alloc((size_t)ND_ * EMB_ * 2);
  unsigned short* Wtv = (unsigned short*)alloc((size_t)ND_ * EMB_ * 2);
  unsigned short* Qb  = (unsigned short*)alloc((size_t)B_ * T_ * ND_ * 2);
  unsigned short* Kb  = (unsigned short*)alloc((size_t)B_ * T_ * ND_ * 2);
  unsigned short* Vt  = (unsigned short*)alloc((size_t)B_ * ND_ * T_ * 2);
  float* colmax = (float*)alloc((size_t)B_ * T_ * 4);
  float* colinv = (float*)alloc((size_t)B_ * T_ * 4);
  float* pm     = (float*)alloc((size_t)B_ * NTB2 * NTB2 * 256 * 4);
  float* pl     = (float*)alloc((size_t)B_ * NTB2 * NTB2 * 256 * 4);
  unsigned short* Pb  = (unsigned short*)alloc((size_t)B_ * T_ * T_ * 2);
  if (off > ws_size) return;

  hipFuncSetAttribute((const void*)&gemm_xw256_kernel<0>,
                      hipFuncAttributeMaxDynamicSharedMemorySize, 131072);
  hipFuncSetAttribute((const void*)&gemm_xw256_kernel<1>,
                      hipFuncAttributeMaxDynamicSharedMemorySize, 131072);
  hipFuncSetAttribute((const void*)&scoretile256_kernel,
                      hipFuncAttributeMaxDynamicSharedMemorySize, 131072);
  hipFuncSetAttribute((const void*)&gemm_pv256_kernel,
                      hipFuncAttributeMaxDynamicSharedMemorySize, 98304);

  hipLaunchKernelGGL(cvt_x_kernel, dim3((B_ * T_ * EMB_) / 1024), dim3(256), 0, stream, X, Xb);
  hipLaunchKernelGGL(transpose_w_kernel, dim3(32, 32), dim3(256), 0, stream, Wq, Wtq, 0.03125f);
  hipLaunchKernelGGL(transpose_w_kernel, dim3(32, 32), dim3(256), 0, stream, Wk, Wtk, 1.0f);
  hipLaunchKernelGGL(transpose_w_kernel, dim3(32, 32), dim3(256), 0, stream, Wv, Wtv, 1.0f);
  hipLaunchKernelGGL((gemm_xw256_kernel<0>), dim3(ND_ / 256, (B_ * T_) / 256), dim3(512), 131072, stream, Xb, Wtq, Qb);
  hipLaunchKernelGGL((gemm_xw256_kernel<0>), dim3(ND_ / 256, (B_ * T_) / 256), dim3(512), 131072, stream, Xb, Wtk, Kb);
  hipLaunchKernelGGL((gemm_xw256_kernel<1>), dim3(ND_ / 256, (B_ * T_) / 256), dim3(512), 131072, stream, Xb, Wtv, Vt);
  hipLaunchKernelGGL(scoretile256_kernel, dim3(NPAIR2, B_), dim3(512), 131072, stream, Qb, Kb, Pb, pm, pl);
  hipLaunchKernelGGL(colreduce_kernel, dim3(NTB2, B_), dim3(256), 0, stream, pm, pl, colmax, colinv);
  hipLaunchKernelGGL(pscale_kernel, dim3(NPAIR, B_), dim3(256), 0, stream, Pb, colmax, colinv);
  hipLaunchKernelGGL(gemm_pv256_kernel, dim3(NTB2, ND_ / 256, B_), dim3(512), 98304, stream, Pb, Vt, out);
}

// Round 5
// 302.376 us; speedup vs baseline: 2.3013x; 1.0094x over previous
//
#include <hip/hip_runtime.h>
#include <hip/hip_bf16.h>

#define B_   8
#define T_   2048
#define EMB_ 1024
#define ND_  1024
#define NTB  16     // T_/128
#define NPAIR 136   // 128-granularity lower-tri pairs
#define NTB2 8      // T_/256
#define NPAIR2 36   // 256-granularity lower-tri pairs

typedef __attribute__((ext_vector_type(8))) short   bf8_t;   // 8 bf16 elements (4 VGPRs)
typedef __attribute__((ext_vector_type(4))) float   f32x4;

__device__ __forceinline__ unsigned short f2bf(float f) {
  union { float f; unsigned int u; } c; c.f = f;
  unsigned int u = c.u;
  unsigned int r = (u + 0x7FFFu + ((u >> 16) & 1u)) >> 16;
  return (unsigned short)r;
}

__device__ __forceinline__ float bf2f(unsigned short b) {
  union { unsigned int u; float f; } c; c.u = ((unsigned int)b) << 16;
  return c.f;
}

__device__ __forceinline__ void gload_lds16(const unsigned short* g, unsigned short* l) {
  __builtin_amdgcn_global_load_lds(
      (const __attribute__((address_space(1))) unsigned int*)g,
      (__attribute__((address_space(3))) unsigned int*)l,
      16, 0, 0);
}

__device__ __forceinline__ void tri_decode(int p, int& tblk, int& sblk) {
  int t = (int)((sqrtf(8.0f * (float)p + 1.0f) - 1.0f) * 0.5f);
  while ((t + 1) * (t + 2) / 2 <= p) ++t;
  while (t * (t + 1) / 2 > p) --t;
  tblk = t;
  sblk = p - t * (t + 1) / 2;
}

#define SB0() __builtin_amdgcn_sched_barrier(0)
#define BAR() __builtin_amdgcn_s_barrier()

// Stage one 128x64 bf16 half-tile. Dest LDS linear; source column pre-XOR-swizzled
// so lds[row][ce] == G[row][k0 + (ce ^ ((row&7)<<3))].
__device__ __forceinline__ void stage_half(const unsigned short* __restrict__ g, int lda,
                                           unsigned short* lhalf, int wave, int lane) {
  const int r3 = lane >> 3, c3 = lane & 7;
  const int colsw = ((c3 ^ r3) << 3);
#pragma unroll
  for (int j = 0; j < 2; ++j) {
    const int row = wave * 8 + r3 + 64 * j;
    gload_lds16(g + (size_t)row * lda + colsw, lhalf + wave * 512 + j * 4096);
  }
}

// Read one bf16x8 MFMA fragment at half-local row r, K-subtile ks, undoing swizzle.
__device__ __forceinline__ bf8_t read_frag(const unsigned short* half, int r, int ks, int lane) {
  const int col = (((ks) << 5) + ((lane >> 4) << 3)) ^ ((r & 7) << 3);
  return *(const bf8_t*)(half + r * 64 + col);
}

// Epilogue LDS swizzle: XOR on byte offset within a 512-B row, 16-B granules.
__device__ __forceinline__ int swz_ep(int x) { return ((x >> 1) & 7) << 4; }

// ---------------- X -> bf16 ----------------
__global__ void __launch_bounds__(256) cvt_x_kernel(const float* __restrict__ in,
                                                    unsigned short* __restrict__ out) {
  const int i = (blockIdx.x * 256 + threadIdx.x) * 4;
  float4 v = *(const float4*)(in + i);
  ushort4 o = make_ushort4(f2bf(v.x), f2bf(v.y), f2bf(v.z), f2bf(v.w));
  *(ushort4*)(out + i) = o;
}

// ---------------- W [K][N] f32 -> Wt [N][K] bf16 (optionally scaled) ----------------
__global__ void __launch_bounds__(256) transpose_w_kernel(const float* __restrict__ W,
                                                          unsigned short* __restrict__ Wt,
                                                          float cscale) {
  __shared__ unsigned short tile[32][33];
  const int n0 = blockIdx.x * 32, k0 = blockIdx.y * 32;
  const int tx = threadIdx.x & 31, ty = threadIdx.x >> 5;
#pragma unroll
  for (int r = 0; r < 32; r += 8) {
    float v = W[(size_t)(k0 + ty + r) * ND_ + n0 + tx];
    tile[tx][ty + r] = f2bf(v * cscale);
  }
  __syncthreads();
#pragma unroll
  for (int r = 0; r < 32; r += 8) {
    Wt[(size_t)(n0 + ty + r) * EMB_ + k0 + tx] = tile[ty + r][tx];
  }
}

// ================= 256x256 8-phase core, distance-2 prefetch =================
// B halves of a K-tile are fully read at q0 -> stage B(t+2) at q1.
// A halves fully read by end of q2 -> stage A(t+2) at q3.
// vmcnt(8): waits tile t+1 complete (8 loads of t+2 stay in flight). 8-phase slack.
#define LDSA(d, h) (lds256 + ((d) * 2 + (h)) * 8192)
#define LDSB(d, h) (lds256 + 32768 + ((d) * 2 + (h)) * 8192)

#define MFMA_QUAD(MB, AF, AOFF) do { \
  __builtin_amdgcn_s_setprio(1); \
  _Pragma("unroll") \
  for (int mi = 0; mi < 2; ++mi) \
    _Pragma("unroll") \
    for (int nf = 0; nf < 4; ++nf) \
      _Pragma("unroll") \
      for (int ks = 0; ks < 2; ++ks) \
        acc[(MB) * 2 + mi][nf] = __builtin_amdgcn_mfma_f32_16x16x32_bf16( \
            (AF)[(AOFF) + mi][ks], bfr[nf][ks], acc[(MB) * 2 + mi][nf], 0, 0, 0); \
  __builtin_amdgcn_s_setprio(0); \
} while (0)

#define GEMM256_LOOP(ABASE, BBASE, LDK) \
  stage_half((ABASE),                             (LDK), LDSA(0, 0), wave, lane); \
  stage_half((ABASE) + (size_t)128 * (LDK),       (LDK), LDSA(0, 1), wave, lane); \
  stage_half((BBASE),                             (LDK), LDSB(0, 0), wave, lane); \
  stage_half((BBASE) + (size_t)128 * (LDK),       (LDK), LDSB(0, 1), wave, lane); \
  stage_half((BBASE) + 64,                        (LDK), LDSB(1, 0), wave, lane); \
  stage_half((BBASE) + (size_t)128 * (LDK) + 64,  (LDK), LDSB(1, 1), wave, lane); \
  stage_half((ABASE) + 64,                        (LDK), LDSA(1, 0), wave, lane); \
  stage_half((ABASE) + (size_t)128 * (LDK) + 64,  (LDK), LDSA(1, 1), wave, lane); \
  asm volatile("s_waitcnt vmcnt(8)" ::: "memory"); \
  SB0(); BAR(); SB0(); \
  for (int t = 0; t < 16; ++t) { \
    const int d = t & 1; \
    const unsigned short* Ah = LDSA(d, wm); \
    const unsigned short* Bh = LDSB(d, wn >> 1); \
    bf8_t bfr[4][2], af[4][2]; \
    _Pragma("unroll") \
    for (int nf = 0; nf < 4; ++nf) \
      _Pragma("unroll") \
      for (int ks = 0; ks < 2; ++ks) bfr[nf][ks] = read_frag(Bh, brow + nf * 16, ks, lane); \
    _Pragma("unroll") \
    for (int mf = 0; mf < 4; ++mf) \
      _Pragma("unroll") \
      for (int ks = 0; ks < 2; ++ks) af[mf][ks] = read_frag(Ah, arow + mf * 16, ks, lane); \
    SB0(); BAR(); SB0(); \
    MFMA_QUAD(0, af, 0); \
    SB0(); \
    asm volatile("s_waitcnt lgkmcnt(0)" ::: "memory"); \
    SB0(); BAR(); SB0(); \
    if (t < 14) { \
      stage_half((BBASE) + (size_t)(t + 2) * 64,                     (LDK), LDSB(d, 0), wave, lane); \
      stage_half((BBASE) + (size_t)128 * (LDK) + (size_t)(t + 2) * 64,(LDK), LDSB(d, 1), wave, lane); \
    } \
    SB0(); BAR(); SB0(); \
    MFMA_QUAD(1, af, 2); \
    SB0(); BAR(); SB0(); \
    bf8_t af2[4][2]; \
    _Pragma("unroll") \
    for (int mf = 0; mf < 4; ++mf) \
      _Pragma("unroll") \
      for (int ks = 0; ks < 2; ++ks) af2[mf][ks] = read_frag(Ah, arow + (mf + 4) * 16, ks, lane); \
    SB0(); BAR(); SB0(); \
    MFMA_QUAD(2, af2, 0); \
    SB0(); \
    asm volatile("s_waitcnt lgkmcnt(0)" ::: "memory"); \
    SB0(); BAR(); SB0(); \
    if (t < 14) { \
      stage_half((ABASE) + (size_t)(t + 2) * 64,                     (LDK), LDSA(d, 0), wave, lane); \
      stage_half((ABASE) + (size_t)128 * (LDK) + (size_t)(t + 2) * 64,(LDK), LDSA(d, 1), wave, lane); \
      asm volatile("s_waitcnt vmcnt(8)" ::: "memory"); \
    } else if (t == 14) { \
      asm volatile("s_waitcnt vmcnt(0)" ::: "memory"); \
    } \
    SB0(); BAR(); SB0(); \
    MFMA_QUAD(3, af2, 2); \
    SB0(); BAR(); SB0(); \
  }

// Epilogue: acc -> LDS (swizzled), barrier, coalesced b128 readback.
// TRANS=0: lds[r][c] (row-major C); TRANS=1: lds[c][r] (for Vt column-major store).
#define ACC_TO_LDS(TRANS, MASKED) do { \
  _Pragma("unroll") \
  for (int mf = 0; mf < 8; ++mf) \
    _Pragma("unroll") \
    for (int nf = 0; nf < 4; ++nf) \
      _Pragma("unroll") \
      for (int q = 0; q < 4; ++q) { \
        const int r = wm * 128 + mf * 16 + cr4 + q; \
        const int c = wn * 64 + nf * 16 + cc; \
        unsigned short bv; \
        if (MASKED) { \
          const bool ok = !diag || (t0 + r >= s0 + c); \
          bv = ok ? f2bf(acc[mf][nf][q]) : (unsigned short)0; \
        } else { \
          bv = f2bf(acc[mf][nf][q]); \
        } \
        const int byte = (TRANS) ? (c * 512 + ((r * 2) ^ swz_ep(c))) \
                                 : (r * 512 + ((c * 2) ^ swz_ep(r))); \
        lds256[byte >> 1] = bv; \
      } \
} while (0)

template <int OUTMODE>
__global__ void __launch_bounds__(512, 2)
gemm_xw256_kernel(const unsigned short* __restrict__ A,
                  const unsigned short* __restrict__ Bt,
                  unsigned short* __restrict__ C) {
  extern __shared__ unsigned short lds256[];
  const int tid = threadIdx.x, lane = tid & 63, wave = tid >> 6;
  const int wm = wave >> 2, wn = wave & 3;
  const int m0 = blockIdx.y * 256, n0 = blockIdx.x * 256;
  const unsigned short* Ab = A + (size_t)m0 * EMB_;
  const unsigned short* Bb = Bt + (size_t)n0 * EMB_;
  f32x4 acc[8][4];
#pragma unroll
  for (int i = 0; i < 8; ++i)
#pragma unroll
    for (int j = 0; j < 4; ++j)
#pragma unroll
      for (int q = 0; q < 4; ++q) acc[i][j][q] = 0.f;
  const int arow = lane & 15;
  const int brow = (wn & 1) * 64 + (lane & 15);

  GEMM256_LOOP(Ab, Bb, EMB_)

  const int cc = lane & 15, cr4 = (lane >> 4) << 2;
  const bool diag = false; const int t0 = 0, s0 = 0; (void)diag; (void)t0; (void)s0;
  ACC_TO_LDS(OUTMODE == 1, false);
  __syncthreads();
  if (OUTMODE == 0) {
#pragma unroll
    for (int p = 0; p < 16; ++p) {
      const int o = p * 8192 + tid * 16;
      const int ri = o >> 9, cb = o & 511;
      const bf8_t v = *(const bf8_t*)(lds256 + (((o & ~511) | (cb ^ swz_ep(ri))) >> 1));
      *(bf8_t*)(C + (size_t)(m0 + ri) * ND_ + n0 + (cb >> 1)) = v;
    }
  } else {
    const int bb = m0 >> 11, tt0 = m0 & 2047;
#pragma unroll
    for (int p = 0; p < 16; ++p) {
      const int o = p * 8192 + tid * 16;
      const int ci = o >> 9, rb = o & 511;  // ci = output col, rb = row-bytes
      const bf8_t v = *(const bf8_t*)(lds256 + (((o & ~511) | (rb ^ swz_ep(ci))) >> 1));
      *(bf8_t*)(C + ((size_t)bb * ND_ + n0 + ci) * T_ + tt0 + (rb >> 1)) = v;
    }
  }
}

// --------- S tiles at 256 granularity + column partial stats (distance-2 core) ---------
// 1D grid of 288: batch = id & 7 (XCD-chunked), pair = id >> 3.
__global__ void __launch_bounds__(512, 2)
scoretile256_kernel(const unsigned short* __restrict__ Qb,
                    const unsigned short* __restrict__ Kb,
                    unsigned short* __restrict__ Sb,
                    float* __restrict__ pm,
                    float* __restrict__ pl) {
  extern __shared__ unsigned short lds256[];
  const int b = blockIdx.x & 7;
  int tr, sr;
  tri_decode(blockIdx.x >> 3, tr, sr);
  const int tid = threadIdx.x, lane = tid & 63, wave = tid >> 6;
  const int wm = wave >> 2, wn = wave & 3;
  const int t0 = tr * 256, s0 = sr * 256;
  const unsigned short* Ab = Qb + ((size_t)b * T_ + t0) * ND_;
  const unsigned short* Bb = Kb + ((size_t)b * T_ + s0) * ND_;
  f32x4 acc[8][4];
#pragma unroll
  for (int i = 0; i < 8; ++i)
#pragma unroll
    for (int j = 0; j < 4; ++j)
#pragma unroll
      for (int q = 0; q < 4; ++q) acc[i][j][q] = 0.f;
  const int arow = lane & 15;
  const int brow = (wn & 1) * 64 + (lane & 15);

  GEMM256_LOOP(Ab, Bb, ND_)

  // ---- stats (registers) + masked S into LDS ----
  const int cc = lane & 15, cr4 = (lane >> 4) << 2;
  const bool diag = (tr == sr);
  float rm[4], rl[4];
#pragma unroll
  for (int nf = 0; nf < 4; ++nf) { rm[nf] = -1e30f; rl[nf] = 0.f; }
#pragma unroll
  for (int mf = 0; mf < 8; ++mf)
#pragma unroll
    for (int nf = 0; nf < 4; ++nf)
#pragma unroll
      for (int q = 0; q < 4; ++q) {
        const int r = wm * 128 + mf * 16 + cr4 + q;
        const int c = wn * 64 + nf * 16 + cc;
        const bool ok = !diag || (t0 + r >= s0 + c);
        const unsigned short bv = ok ? f2bf(acc[mf][nf][q]) : (unsigned short)0;
        lds256[(r * 512 + ((c * 2) ^ swz_ep(r))) >> 1] = bv;
        if (ok) {
          const float v = bf2f(bv);
          const float mm = fmaxf(rm[nf], v);
          rl[nf] = rl[nf] * __expf(rm[nf] - mm) + __expf(v - mm);
          rm[nf] = mm;
        }
      }
  __syncthreads();
  // ---- coalesced S store ----
  unsigned short* Sbase = Sb + (size_t)b * T_ * T_;
#pragma unroll
  for (int p = 0; p < 16; ++p) {
    const int o = p * 8192 + tid * 16;
    const int ri = o >> 9, cb = o & 511;
    const bf8_t v = *(const bf8_t*)(lds256 + (((o & ~511) | (cb ^ swz_ep(ri))) >> 1));
    *(bf8_t*)(Sbase + (size_t)(t0 + ri) * T_ + s0 + (cb >> 1)) = v;
  }
  // ---- cross-lane + cross-wave stat reduction ----
#pragma unroll
  for (int nf = 0; nf < 4; ++nf) {
#pragma unroll
    for (int off = 16; off < 64; off <<= 1) {
      const float om = __shfl_xor(rm[nf], off);
      const float ol = __shfl_xor(rl[nf], off);
      const float mm = fmaxf(rm[nf], om);
      rl[nf] = rl[nf] * __expf(rm[nf] - mm) + ol * __expf(om - mm);
      rm[nf] = mm;
    }
  }
  __syncthreads();              // S readback done; LDS reusable as scratch
  float* red = (float*)lds256;
  if (lane < 16) {
#pragma unroll
    for (int nf = 0; nf < 4; ++nf) {
      red[((wm * 4 + wn) * 4 + nf) * 16 + lane] = rm[nf];
      red[512 + ((wm * 4 + wn) * 4 + nf) * 16 + lane] = rl[nf];
    }
  }
  __syncthreads();
  if (wm == 0 && lane < 16) {
    const size_t base = (((size_t)b * NTB2 + sr) * NTB2 + tr) * 256;
#pragma unroll
    for (int nf = 0; nf < 4; ++nf) {
      const float m0v = red[((0 * 4 + wn) * 4 + nf) * 16 + lane];
      const float l0v = red[512 + ((0 * 4 + wn) * 4 + nf) * 16 + lane];
      const float m1v = red[((1 * 4 + wn) * 4 + nf) * 16 + lane];
      const float l1v = red[512 + ((1 * 4 + wn) * 4 + nf) * 16 + lane];
      const float mm = fmaxf(m0v, m1v);
      const float ll = l0v * __expf(m0v - mm) + l1v * __expf(m1v - mm);
      pm[base + wn * 64 + nf * 16 + lane] = mm;
      pl[base + wn * 64 + nf * 16 + lane] = ll;
    }
  }
}

// ---------------- fold per-tile partials into colmax / colinv ----------------
__global__ void __launch_bounds__(256) colreduce_kernel(const float* __restrict__ pm,
                                                        const float* __restrict__ pl,
                                                        float* __restrict__ colmax,
                                                        float* __restrict__ colinv) {
  const int sr = blockIdx.x, b = blockIdx.y, c = threadIdx.x;
  float m = -1e30f, l = 0.f;
  for (int tr = sr; tr < NTB2; ++tr) {
    const size_t base = (((size_t)b * NTB2 + sr) * NTB2 + tr) * 256;
    const float om = pm[base + c], ol = pl[base + c];
    const float mm = fmaxf(m, om);
    l = l * __expf(m - mm) + ol * __expf(om - mm);
    m = mm;
  }
  colmax[(size_t)b * T_ + sr * 256 + c] = m;
  colinv[(size_t)b * T_ + sr * 256 + c] = 1.0f / l;
}

// ---------------- P = exp(S - m_s) * inv_l_s, in place (128-granularity) ----------------
__global__ void __launch_bounds__(256) pscale_kernel(unsigned short* __restrict__ Pb,
                                                     const float* __restrict__ colmax,
                                                     const float* __restrict__ colinv) {
  int tblk, sblk;
  tri_decode(blockIdx.x, tblk, sblk);
  const int b = blockIdx.y;
  const int s0 = sblk * 128, t0 = tblk * 128;
  const int tid = threadIdx.x;
  const int col8 = (tid & 15) * 8;
  const int rbase = tid >> 4;
  unsigned short* Pbase = Pb + (size_t)b * T_ * T_;
  float ms[8], inv[8];
#pragma unroll
  for (int j = 0; j < 8; ++j) {
    ms[j]  = colmax[(size_t)b * T_ + s0 + col8 + j];
    inv[j] = colinv[(size_t)b * T_ + s0 + col8 + j];
  }
  const bool diag = (tblk == sblk);
  for (int r = rbase; r < 128; r += 16) {
    const int t = t0 + r;
    unsigned short* p = Pbase + (size_t)t * T_ + s0 + col8;
    bf8_t v = *(bf8_t*)p;
#pragma unroll
    for (int j = 0; j < 8; ++j) {
      float pv = 0.f;
      if (!diag || t >= s0 + col8 + j) {
        pv = __expf(bf2f((unsigned short)v[j]) - ms[j]) * inv[j];
      }
      v[j] = (short)f2bf(pv);
    }
    *(bf8_t*)p = v;
  }
}

// ========== PV: BM=128 x BN=256, 3 halves/K-tile, distance-2 prefetch ==========
#define MFMA_Q8(MB) do { \
  __builtin_amdgcn_s_setprio(1); \
  _Pragma("unroll") \
  for (int nf = 0; nf < 4; ++nf) \
    _Pragma("unroll") \
    for (int ks = 0; ks < 2; ++ks) \
      acc[(MB)][nf] = __builtin_amdgcn_mfma_f32_16x16x32_bf16( \
          af[(MB)][ks], bfr[nf][ks], acc[(MB)][nf], 0, 0, 0); \
  __builtin_amdgcn_s_setprio(0); \
} while (0)

__device__ __forceinline__ void pv_segment(const unsigned short* __restrict__ Ab,
                                           const unsigned short* __restrict__ Bb,
                                           float* __restrict__ Cb,
                                           int ktiles, unsigned short* lds256,
                                           int lane, int wave) {
  const int wm = wave >> 2, wn = wave & 3;  // wm: t-half (0..1), wn: d-quarter (0..3)
  const int arow = lane & 15;
  f32x4 acc[4][4];
#pragma unroll
  for (int i = 0; i < 4; ++i)
#pragma unroll
    for (int j = 0; j < 4; ++j)
#pragma unroll
      for (int q = 0; q < 4; ++q) acc[i][j][q] = 0.f;

  // Prologue: tiles 0 and 1 (A, B0, B1 each).
  stage_half(Ab,                           T_, lds256,                     wave, lane);
  stage_half(Bb,                           T_, lds256 + 16384,             wave, lane);
  stage_half(Bb + (size_t)128 * T_,        T_, lds256 + 16384 + 8192,      wave, lane);
  stage_half(Ab + 64,                      T_, lds256 + 8192,              wave, lane);
  stage_half(Bb + 64,                      T_, lds256 + 16384 + 2 * 8192,  wave, lane);
  stage_half(Bb + (size_t)128 * T_ + 64,   T_, lds256 + 16384 + 3 * 8192,  wave, lane);
  asm volatile("s_waitcnt vmcnt(6)" ::: "memory");
  SB0(); BAR(); SB0();

  for (int t = 0; t < ktiles; ++t) {
    const int d = t & 1;
    const unsigned short* Ah = lds256 + d * 8192;
    const unsigned short* Bh = lds256 + 16384 + (d * 2 + (wn >> 1)) * 8192;
    // q0: all 16 frag reads (A and B halves fully consumed here)
    bf8_t bfr[4][2], af[4][2];
#pragma unroll
    for (int nf = 0; nf < 4; ++nf)
#pragma unroll
      for (int ks = 0; ks < 2; ++ks)
        bfr[nf][ks] = read_frag(Bh, (wn & 1) * 64 + nf * 16 + arow, ks, lane);
#pragma unroll
    for (int mf = 0; mf < 4; ++mf)
#pragma unroll
      for (int ks = 0; ks < 2; ++ks)
        af[mf][ks] = read_frag(Ah, wm * 64 + mf * 16 + arow, ks, lane);
    SB0(); BAR(); SB0();
    MFMA_Q8(0);
    SB0();
    asm volatile("s_waitcnt lgkmcnt(0)" ::: "memory");
    SB0(); BAR(); SB0();
    // q1: stage A(t+2), B0(t+2)
    if (t < ktiles - 2) {
      stage_half(Ab + (size_t)(t + 2) * 64, T_, lds256 + d * 8192, wave, lane);
      stage_half(Bb + (size_t)(t + 2) * 64, T_, lds256 + 16384 + (d * 2) * 8192, wave, lane);
    }
    SB0(); BAR(); SB0();
    MFMA_Q8(1);
    SB0(); BAR(); SB0();
    // q2: stage B1(t+2)
    if (t < ktiles - 2)
      stage_half(Bb + (size_t)128 * T_ + (size_t)(t + 2) * 64, T_, lds256 + 16384 + (d * 2 + 1) * 8192, wave, lane);
    SB0(); BAR(); SB0();
    MFMA_Q8(2);
    SB0(); BAR(); SB0();
    // q3: counted vmcnt only
    if (t < ktiles - 2)      { asm volatile("s_waitcnt vmcnt(6)" ::: "memory"); }
    else if (t == ktiles - 2){ asm volatile("s_waitcnt vmcnt(0)" ::: "memory"); }
    SB0(); BAR(); SB0();
    MFMA_Q8(3);
    SB0(); BAR(); SB0();
  }

  const int cc = lane & 15, cr4 = (lane >> 4) << 2;
#pragma unroll
  for (int mf = 0; mf < 4; ++mf)
#pragma unroll
    for (int nf = 0; nf < 4; ++nf)
#pragma unroll
      for (int q = 0; q < 4; ++q) {
        const int row = wm * 64 + mf * 16 + cr4 + q;
        const int col = wn * 64 + nf * 16 + cc;
        Cb[(size_t)row * ND_ + col] = acc[mf][nf][q];
      }
}

// 1D grid 256: b = id & 7 (XCD-chunked), pair = (id>>3)&7, ncol = id>>6.
__global__ void __launch_bounds__(512, 2)
gemm_pv256_kernel(const unsigned short* __restrict__ Pb,
                  const unsigned short* __restrict__ Vt,
                  float* __restrict__ out) {
  extern __shared__ unsigned short lds256[];
  const int b = blockIdx.x & 7;
  const int pair = (blockIdx.x >> 3) & 7;
  const int ncol = blockIdx.x >> 6;
  const int tid = threadIdx.x, lane = tid & 63, wave = tid >> 6;
  const int tbs[2] = {pair, 15 - pair};
#pragma unroll
  for (int si = 0; si < 2; ++si) {
    const int tb = tbs[si];
    const int ktiles = 2 * tb + 2;
    pv_segment(Pb + (size_t)b * T_ * T_ + (size_t)tb * 128 * T_,
               Vt + (size_t)b * ND_ * T_ + (size_t)ncol * 256 * T_,
               out + (size_t)b * T_ * ND_ + (size_t)tb * 128 * ND_ + ncol * 256,
               ktiles, lds256, lane, wave);
  }
}

extern "C" void kernel_launch(void* const* d_in, const int* in_sizes, int n_in,
                              void* d_out, int out_size, void* d_ws, size_t ws_size,
                              hipStream_t stream) {
  const float* X  = (const float*)d_in[0];
  const float* Wq = (const float*)d_in[1];
  const float* Wk = (const float*)d_in[2];
  const float* Wv = (const float*)d_in[3];
  float* out = (float*)d_out;
  (void)in_sizes; (void)n_in; (void)out_size;

  char* ws = (char*)d_ws;
  size_t off = 0;
  auto alloc = [&](size_t bytes) {
    void* p = ws + off;
    off += (bytes + 255) & ~(size_t)255;
    return p;
  };
  unsigned short* Xb  = (unsigned short*)alloc((size_t)B_ * T_ * EMB_ * 2);
  unsigned short* Wtq = (unsigned short*)alloc((size_t)ND_ * EMB_ * 2);
  unsigned short* Wtk = (unsigned short*)alloc((size_t)ND_ * EMB_ * 2);
  unsigned short* Wtv = (unsigned short*)alloc((size_t)ND_ * EMB_ * 2);
  unsigned short* Qb  = (unsigned short*)alloc((size_t)B_ * T_ * ND_ * 2);
  unsigned short* Kb  = (unsigned short*)alloc((size_t)B_ * T_ * ND_ * 2);
  unsigned short* Vt  = (unsigned short*)alloc((size_t)B_ * ND_ * T_ * 2);
  float* colmax = (float*)alloc((size_t)B_ * T_ * 4);
  float* colinv = (float*)alloc((size_t)B_ * T_ * 4);
  float* pm     = (float*)alloc((size_t)B_ * NTB2 * NTB2 * 256 * 4);
  float* pl     = (float*)alloc((size_t)B_ * NTB2 * NTB2 * 256 * 4);
  unsigned short* Pb  = (unsigned short*)alloc((size_t)B_ * T_ * T_ * 2);
  if (off > ws_size) return;

  hipFuncSetAttribute((const void*)&gemm_xw256_kernel<0>,
                      hipFuncAttributeMaxDynamicSharedMemorySize, 131072);
  hipFuncSetAttribute((const void*)&gemm_xw256_kernel<1>,
                      hipFuncAttributeMaxDynamicSharedMemorySize, 131072);
  hipFuncSetAttribute((const void*)&scoretile256_kernel,
                      hipFuncAttributeMaxDynamicSharedMemorySize, 131072);
  hipFuncSetAttribute((const void*)&gemm_pv256_kernel,
                      hipFuncAttributeMaxDynamicSharedMemorySize, 98304);

  hipLaunchKernelGGL(cvt_x_kernel, dim3((B_ * T_ * EMB_) / 1024), dim3(256), 0, stream, X, Xb);
  hipLaunchKernelGGL(transpose_w_kernel, dim3(32, 32), dim3(256), 0, stream, Wq, Wtq, 0.03125f);
  hipLaunchKernelGGL(transpose_w_kernel, dim3(32, 32), dim3(256), 0, stream, Wk, Wtk, 1.0f);
  hipLaunchKernelGGL(transpose_w_kernel, dim3(32, 32), dim3(256), 0, stream, Wv, Wtv, 1.0f);
  hipLaunchKernelGGL((gemm_xw256_kernel<0>), dim3(ND_ / 256, (B_ * T_) / 256), dim3(512), 131072, stream, Xb, Wtq, Qb);
  hipLaunchKernelGGL((gemm_xw256_kernel<0>), dim3(ND_ / 256, (B_ * T_) / 256), dim3(512), 131072, stream, Xb, Wtk, Kb);
  hipLaunchKernelGGL((gemm_xw256_kernel<1>), dim3(ND_ / 256, (B_ * T_) / 256), dim3(512), 131072, stream, Xb, Wtv, Vt);
  hipLaunchKernelGGL(scoretile256_kernel, dim3(NPAIR2 * B_), dim3(512), 131072, stream, Qb, Kb, Pb, pm, pl);
  hipLaunchKernelGGL(colreduce_kernel, dim3(NTB2, B_), dim3(256), 0, stream, pm, pl, colmax, colinv);
  hipLaunchKernelGGL(pscale_kernel, dim3(NPAIR, B_), dim3(256), 0, stream, Pb, colmax, colinv);
  hipLaunchKernelGGL(gemm_pv256_kernel, dim3(NTB2 * 4 * B_), dim3(512), 98304, stream, Pb, Vt, out);
}

// Round 6
// 284.850 us; speedup vs baseline: 2.4429x; 1.0615x over previous
//
#include <hip/hip_runtime.h>
#include <hip/hip_bf16.h>

#define B_   8
#define T_   2048
#define EMB_ 1024
#define ND_  1024
#define NTB2 8      // T_/256

typedef __attribute__((ext_vector_type(8))) short   bf8_t;   // 8 bf16 elements (4 VGPRs)
typedef __attribute__((ext_vector_type(4))) float   f32x4;

__device__ __forceinline__ unsigned short f2bf(float f) {
  union { float f; unsigned int u; } c; c.f = f;
  unsigned int u = c.u;
  unsigned int r = (u + 0x7FFFu + ((u >> 16) & 1u)) >> 16;
  return (unsigned short)r;
}

__device__ __forceinline__ float bf2f(unsigned short b) {
  union { unsigned int u; float f; } c; c.u = ((unsigned int)b) << 16;
  return c.f;
}

__device__ __forceinline__ void gload_lds16(const unsigned short* g, unsigned short* l) {
  __builtin_amdgcn_global_load_lds(
      (const __attribute__((address_space(1))) unsigned int*)g,
      (__attribute__((address_space(3))) unsigned int*)l,
      16, 0, 0);
}

#define SB0() __builtin_amdgcn_sched_barrier(0)
#define BAR() __builtin_amdgcn_s_barrier()

// Stage one 128x64 bf16 half-tile. Dest LDS linear; source column pre-XOR-swizzled
// so lds[row][ce] == G[row][k0 + (ce ^ ((row&7)<<3))].
__device__ __forceinline__ void stage_half(const unsigned short* __restrict__ g, int lda,
                                           unsigned short* lhalf, int wave, int lane) {
  const int r3 = lane >> 3, c3 = lane & 7;
  const int colsw = ((c3 ^ r3) << 3);
#pragma unroll
  for (int j = 0; j < 2; ++j) {
    const int row = wave * 8 + r3 + 64 * j;
    gload_lds16(g + (size_t)row * lda + colsw, lhalf + wave * 512 + j * 4096);
  }
}

// Read one bf16x8 MFMA fragment at half-local row r, K-subtile ks, undoing swizzle.
__device__ __forceinline__ bf8_t read_frag(const unsigned short* half, int r, int ks, int lane) {
  const int col = (((ks) << 5) + ((lane >> 4) << 3)) ^ ((r & 7) << 3);
  return *(const bf8_t*)(half + r * 64 + col);
}

// Epilogue LDS swizzle: XOR on byte offset within a 512-B row, 16-B granules.
__device__ __forceinline__ int swz_ep(int x) { return ((x >> 1) & 7) << 4; }

// ---------------- X -> bf16 ----------------
__global__ void __launch_bounds__(256) cvt_x_kernel(const float* __restrict__ in,
                                                    unsigned short* __restrict__ out) {
  const int i = (blockIdx.x * 256 + threadIdx.x) * 4;
  float4 v = *(const float4*)(in + i);
  ushort4 o = make_ushort4(f2bf(v.x), f2bf(v.y), f2bf(v.z), f2bf(v.w));
  *(ushort4*)(out + i) = o;
}

// ---------------- W [K][N] f32 -> Wt [N][K] bf16 (optionally scaled) ----------------
__global__ void __launch_bounds__(256) transpose_w_kernel(const float* __restrict__ W,
                                                          unsigned short* __restrict__ Wt,
                                                          float cscale) {
  __shared__ unsigned short tile[32][33];
  const int n0 = blockIdx.x * 32, k0 = blockIdx.y * 32;
  const int tx = threadIdx.x & 31, ty = threadIdx.x >> 5;
#pragma unroll
  for (int r = 0; r < 32; r += 8) {
    float v = W[(size_t)(k0 + ty + r) * ND_ + n0 + tx];
    tile[tx][ty + r] = f2bf(v * cscale);
  }
  __syncthreads();
#pragma unroll
  for (int r = 0; r < 32; r += 8) {
    Wt[(size_t)(n0 + ty + r) * EMB_ + k0 + tx] = tile[ty + r][tx];
  }
}

// ================= shared MFMA quad macros =================
#define MFMA_QUAD(MB, AF, AOFF) do { \
  __builtin_amdgcn_s_setprio(1); \
  _Pragma("unroll") \
  for (int mi = 0; mi < 2; ++mi) \
    _Pragma("unroll") \
    for (int nf = 0; nf < 4; ++nf) \
      _Pragma("unroll") \
      for (int ks = 0; ks < 2; ++ks) \
        acc[(MB) * 2 + mi][nf] = __builtin_amdgcn_mfma_f32_16x16x32_bf16( \
            (AF)[(AOFF) + mi][ks], bfr[nf][ks], acc[(MB) * 2 + mi][nf], 0, 0, 0); \
  __builtin_amdgcn_s_setprio(0); \
} while (0)

#define MFMA_Q8(MB) do { \
  __builtin_amdgcn_s_setprio(1); \
  _Pragma("unroll") \
  for (int nf = 0; nf < 4; ++nf) \
    _Pragma("unroll") \
    for (int ks = 0; ks < 2; ++ks) \
      acc[(MB)][nf] = __builtin_amdgcn_mfma_f32_16x16x32_bf16( \
          af[(MB)][ks], bfr[nf][ks], acc[(MB)][nf], 0, 0, 0); \
  __builtin_amdgcn_s_setprio(0); \
} while (0)

// ================= 256x256 8-phase core, distance-2 prefetch (proven; xw only) =========
#define LDSA(d, h) (lds256 + ((d) * 2 + (h)) * 8192)
#define LDSB(d, h) (lds256 + 32768 + ((d) * 2 + (h)) * 8192)

#define GEMM256_LOOP(ABASE, BBASE, LDK) \
  stage_half((ABASE),                             (LDK), LDSA(0, 0), wave, lane); \
  stage_half((ABASE) + (size_t)128 * (LDK),       (LDK), LDSA(0, 1), wave, lane); \
  stage_half((BBASE),                             (LDK), LDSB(0, 0), wave, lane); \
  stage_half((BBASE) + (size_t)128 * (LDK),       (LDK), LDSB(0, 1), wave, lane); \
  stage_half((BBASE) + 64,                        (LDK), LDSB(1, 0), wave, lane); \
  stage_half((BBASE) + (size_t)128 * (LDK) + 64,  (LDK), LDSB(1, 1), wave, lane); \
  stage_half((ABASE) + 64,                        (LDK), LDSA(1, 0), wave, lane); \
  stage_half((ABASE) + (size_t)128 * (LDK) + 64,  (LDK), LDSA(1, 1), wave, lane); \
  asm volatile("s_waitcnt vmcnt(8)" ::: "memory"); \
  SB0(); BAR(); SB0(); \
  for (int t = 0; t < 16; ++t) { \
    const int d = t & 1; \
    const unsigned short* Ah = LDSA(d, wm); \
    const unsigned short* Bh = LDSB(d, wn >> 1); \
    bf8_t bfr[4][2], af[4][2]; \
    _Pragma("unroll") \
    for (int nf = 0; nf < 4; ++nf) \
      _Pragma("unroll") \
      for (int ks = 0; ks < 2; ++ks) bfr[nf][ks] = read_frag(Bh, brow + nf * 16, ks, lane); \
    _Pragma("unroll") \
    for (int mf = 0; mf < 4; ++mf) \
      _Pragma("unroll") \
      for (int ks = 0; ks < 2; ++ks) af[mf][ks] = read_frag(Ah, arow + mf * 16, ks, lane); \
    SB0(); BAR(); SB0(); \
    MFMA_QUAD(0, af, 0); \
    SB0(); \
    asm volatile("s_waitcnt lgkmcnt(0)" ::: "memory"); \
    SB0(); BAR(); SB0(); \
    if (t < 14) { \
      stage_half((BBASE) + (size_t)(t + 2) * 64,                     (LDK), LDSB(d, 0), wave, lane); \
      stage_half((BBASE) + (size_t)128 * (LDK) + (size_t)(t + 2) * 64,(LDK), LDSB(d, 1), wave, lane); \
    } \
    SB0(); BAR(); SB0(); \
    MFMA_QUAD(1, af, 2); \
    SB0(); BAR(); SB0(); \
    bf8_t af2[4][2]; \
    _Pragma("unroll") \
    for (int mf = 0; mf < 4; ++mf) \
      _Pragma("unroll") \
      for (int ks = 0; ks < 2; ++ks) af2[mf][ks] = read_frag(Ah, arow + (mf + 4) * 16, ks, lane); \
    SB0(); BAR(); SB0(); \
    MFMA_QUAD(2, af2, 0); \
    SB0(); \
    asm volatile("s_waitcnt lgkmcnt(0)" ::: "memory"); \
    SB0(); BAR(); SB0(); \
    if (t < 14) { \
      stage_half((ABASE) + (size_t)(t + 2) * 64,                     (LDK), LDSA(d, 0), wave, lane); \
      stage_half((ABASE) + (size_t)128 * (LDK) + (size_t)(t + 2) * 64,(LDK), LDSA(d, 1), wave, lane); \
      asm volatile("s_waitcnt vmcnt(8)" ::: "memory"); \
    } else if (t == 14) { \
      asm volatile("s_waitcnt vmcnt(0)" ::: "memory"); \
    } \
    SB0(); BAR(); SB0(); \
    MFMA_QUAD(3, af2, 2); \
    SB0(); BAR(); SB0(); \
  }

template <int OUTMODE>
__global__ void __launch_bounds__(512, 2)
gemm_xw256_kernel(const unsigned short* __restrict__ A,
                  const unsigned short* __restrict__ Bt,
                  unsigned short* __restrict__ C) {
  extern __shared__ unsigned short lds256[];
  const int tid = threadIdx.x, lane = tid & 63, wave = tid >> 6;
  const int wm = wave >> 2, wn = wave & 3;
  const int m0 = blockIdx.y * 256, n0 = blockIdx.x * 256;
  const unsigned short* Ab = A + (size_t)m0 * EMB_;
  const unsigned short* Bb = Bt + (size_t)n0 * EMB_;
  f32x4 acc[8][4];
#pragma unroll
  for (int i = 0; i < 8; ++i)
#pragma unroll
    for (int j = 0; j < 4; ++j)
#pragma unroll
      for (int q = 0; q < 4; ++q) acc[i][j][q] = 0.f;
  const int arow = lane & 15;
  const int brow = (wn & 1) * 64 + (lane & 15);

  GEMM256_LOOP(Ab, Bb, EMB_)

  const int cc = lane & 15, cr4 = (lane >> 4) << 2;
#pragma unroll
  for (int mf = 0; mf < 8; ++mf)
#pragma unroll
    for (int nf = 0; nf < 4; ++nf)
#pragma unroll
      for (int q = 0; q < 4; ++q) {
        const int r = wm * 128 + mf * 16 + cr4 + q;
        const int c = wn * 64 + nf * 16 + cc;
        const unsigned short bv = f2bf(acc[mf][nf][q]);
        const int byte = (OUTMODE == 1) ? (c * 512 + ((r * 2) ^ swz_ep(c)))
                                        : (r * 512 + ((c * 2) ^ swz_ep(r)));
        lds256[byte >> 1] = bv;
      }
  __syncthreads();
  if (OUTMODE == 0) {
#pragma unroll
    for (int p = 0; p < 16; ++p) {
      const int o = p * 8192 + tid * 16;
      const int ri = o >> 9, cb = o & 511;
      const bf8_t v = *(const bf8_t*)(lds256 + (((o & ~511) | (cb ^ swz_ep(ri))) >> 1));
      *(bf8_t*)(C + (size_t)(m0 + ri) * ND_ + n0 + (cb >> 1)) = v;
    }
  } else {
    const int bb = m0 >> 11, tt0 = m0 & 2047;
#pragma unroll
    for (int p = 0; p < 16; ++p) {
      const int o = p * 8192 + tid * 16;
      const int ci = o >> 9, rb = o & 511;
      const bf8_t v = *(const bf8_t*)(lds256 + (((o & ~511) | (rb ^ swz_ep(ci))) >> 1));
      *(bf8_t*)(C + ((size_t)bb * ND_ + n0 + ci) * T_ + tt0 + (rb >> 1)) = v;
    }
  }
}

// ========== scoretile576: BM=128(t) x BN=256(s) -> P' = exp(S) + column sums ==========
__global__ void __launch_bounds__(512, 2)
scoretile576_kernel(const unsigned short* __restrict__ Qb,
                    const unsigned short* __restrict__ Kb,
                    unsigned short* __restrict__ Pp,
                    float* __restrict__ pm) {
  extern __shared__ unsigned short lds256[];
  const int id = blockIdx.x;
  const int b = id & 7;
  const int r = id >> 3;  // 0..71
  int sc = 0, pfx = 0;
#pragma unroll 8
  for (int i = 0; i < 8; ++i) {
    const int cnt = 16 - 2 * sc;
    if (pfx + cnt <= r) { pfx += cnt; ++sc; }
  }
  const int tr = 2 * sc + (r - pfx);
  const int t0 = tr * 128, s0 = sc * 256;
  const int tid = threadIdx.x, lane = tid & 63, wave = tid >> 6;
  const int wm = wave >> 2, wn = wave & 3;  // wm: t-half, wn: s-quarter
  const int arow = lane & 15;
  const unsigned short* Ab = Qb + ((size_t)b * T_ + t0) * ND_;
  const unsigned short* Bb = Kb + ((size_t)b * T_ + s0) * ND_;
  f32x4 acc[4][4];
#pragma unroll
  for (int i = 0; i < 4; ++i)
#pragma unroll
    for (int j = 0; j < 4; ++j)
#pragma unroll
      for (int q = 0; q < 4; ++q) acc[i][j][q] = 0.f;

  stage_half(Ab,                           ND_, lds256,                     wave, lane);
  stage_half(Bb,                           ND_, lds256 + 16384,             wave, lane);
  stage_half(Bb + (size_t)128 * ND_,       ND_, lds256 + 16384 + 8192,      wave, lane);
  stage_half(Ab + 64,                      ND_, lds256 + 8192,              wave, lane);
  stage_half(Bb + 64,                      ND_, lds256 + 16384 + 2 * 8192,  wave, lane);
  stage_half(Bb + (size_t)128 * ND_ + 64,  ND_, lds256 + 16384 + 3 * 8192,  wave, lane);
  asm volatile("s_waitcnt vmcnt(6)" ::: "memory");
  SB0(); BAR(); SB0();

  for (int t = 0; t < 16; ++t) {
    const int d = t & 1;
    const unsigned short* Ah = lds256 + d * 8192;
    const unsigned short* Bh = lds256 + 16384 + (d * 2 + (wn >> 1)) * 8192;
    bf8_t bfr[4][2], af[4][2];
#pragma unroll
    for (int nf = 0; nf < 4; ++nf)
#pragma unroll
      for (int ks = 0; ks < 2; ++ks)
        bfr[nf][ks] = read_frag(Bh, (wn & 1) * 64 + nf * 16 + arow, ks, lane);
#pragma unroll
    for (int mf = 0; mf < 4; ++mf)
#pragma unroll
      for (int ks = 0; ks < 2; ++ks)
        af[mf][ks] = read_frag(Ah, wm * 64 + mf * 16 + arow, ks, lane);
    SB0(); BAR(); SB0();
    MFMA_Q8(0);
    SB0();
    asm volatile("s_waitcnt lgkmcnt(0)" ::: "memory");
    SB0(); BAR(); SB0();
    if (t < 14) {
      stage_half(Ab + (size_t)(t + 2) * 64, ND_, lds256 + d * 8192, wave, lane);
      stage_half(Bb + (size_t)(t + 2) * 64, ND_, lds256 + 16384 + (d * 2) * 8192, wave, lane);
    }
    SB0(); BAR(); SB0();
    MFMA_Q8(1);
    SB0(); BAR(); SB0();
    if (t < 14)
      stage_half(Bb + (size_t)128 * ND_ + (size_t)(t + 2) * 64, ND_, lds256 + 16384 + (d * 2 + 1) * 8192, wave, lane);
    SB0(); BAR(); SB0();
    MFMA_Q8(2);
    SB0(); BAR(); SB0();
    if (t < 14)      { asm volatile("s_waitcnt vmcnt(6)" ::: "memory"); }
    else if (t == 14){ asm volatile("s_waitcnt vmcnt(0)" ::: "memory"); }
    SB0(); BAR(); SB0();
    MFMA_Q8(3);
    SB0(); BAR(); SB0();
  }

  // ---- epilogue: P' = exp(S) (masked) into LDS + per-column register sums ----
  __syncthreads();
  const int cc = lane & 15, cr4 = (lane >> 4) << 2;
  float csum[4];
#pragma unroll
  for (int nf = 0; nf < 4; ++nf) csum[nf] = 0.f;
#pragma unroll
  for (int mf = 0; mf < 4; ++mf)
#pragma unroll
    for (int nf = 0; nf < 4; ++nf)
#pragma unroll
      for (int q = 0; q < 4; ++q) {
        const int rr = wm * 64 + mf * 16 + cr4 + q;   // 0..127
        const int c  = wn * 64 + nf * 16 + cc;        // 0..255
        const bool ok = (t0 + rr) >= (s0 + c);
        unsigned short bv = 0;
        if (ok) {
          bv = f2bf(__expf(fminf(acc[mf][nf][q], 30.f)));
          csum[nf] += bf2f(bv);
        }
        lds256[(rr * 512 + ((c * 2) ^ swz_ep(rr))) >> 1] = bv;
      }
  __syncthreads();
  unsigned short* Pbase = Pp + (size_t)b * T_ * T_;
#pragma unroll
  for (int p = 0; p < 8; ++p) {
    const int o = p * 8192 + tid * 16;
    const int ri = o >> 9, cb = o & 511;
    const bf8_t v = *(const bf8_t*)(lds256 + (((o & ~511) | (cb ^ swz_ep(ri))) >> 1));
    *(bf8_t*)(Pbase + (size_t)(t0 + ri) * T_ + s0 + (cb >> 1)) = v;
  }
#pragma unroll
  for (int nf = 0; nf < 4; ++nf) {
    csum[nf] += __shfl_xor(csum[nf], 16);
    csum[nf] += __shfl_xor(csum[nf], 32);
  }
  __syncthreads();
  float* red = (float*)lds256;   // [2 wm][4 wn][4 nf][16]
  if (lane < 16) {
#pragma unroll
    for (int nf = 0; nf < 4; ++nf)
      red[((wm * 4 + wn) * 4 + nf) * 16 + lane] = csum[nf];
  }
  __syncthreads();
  if (wm == 0 && lane < 16) {
    const size_t base = (((size_t)b * 8 + sc) * 16 + tr) * 256;
#pragma unroll
    for (int nf = 0; nf < 4; ++nf) {
      const float s = red[((0 * 4 + wn) * 4 + nf) * 16 + lane] +
                      red[((1 * 4 + wn) * 4 + nf) * 16 + lane];
      pm[base + wn * 64 + nf * 16 + lane] = s;
    }
  }
}

// ---------------- c_s = 1 / (sum of per-tile column sums) ----------------
__global__ void __launch_bounds__(256) colreduce_kernel(const float* __restrict__ pm,
                                                        float* __restrict__ colinv) {
  const int sc = blockIdx.x, b = blockIdx.y, c = threadIdx.x;
  float l = 0.f;
  for (int tr = 2 * sc; tr < 16; ++tr)
    l += pm[(((size_t)b * 8 + sc) * 16 + tr) * 256 + c];
  colinv[(size_t)b * T_ + sc * 256 + c] = 1.0f / l;
}

// ---------------- V''[b][d][s] = Vt[b][d][s] * c[b][s] (in place; Vt rebuilt each launch) ----
__global__ void __launch_bounds__(256) vscale_kernel(unsigned short* __restrict__ Vt,
                                                     const float* __restrict__ colinv) {
  const int idx = blockIdx.x * 256 + threadIdx.x;
  const int s8 = (idx * 8) & (T_ - 1);
  const int bd = idx / (T_ / 8);     // b*ND + d
  const int b = bd >> 10;
  unsigned short* p = Vt + (size_t)bd * T_ + s8;
  bf8_t v = *(bf8_t*)p;
#pragma unroll
  for (int j = 0; j < 8; ++j) {
    const float f = bf2f((unsigned short)v[j]) * colinv[(size_t)b * T_ + s8 + j];
    v[j] = (short)f2bf(f);
  }
  *(bf8_t*)p = v;
}

// ========== PV: BM=128 x BN=256, 3 halves/K-tile, distance-2 prefetch (proven) ==========
__device__ __forceinline__ void pv_segment(const unsigned short* __restrict__ Ab,
                                           const unsigned short* __restrict__ Bb,
                                           float* __restrict__ Cb,
                                           int ktiles, unsigned short* lds256,
                                           int lane, int wave) {
  const int wm = wave >> 2, wn = wave & 3;
  const int arow = lane & 15;
  f32x4 acc[4][4];
#pragma unroll
  for (int i = 0; i < 4; ++i)
#pragma unroll
    for (int j = 0; j < 4; ++j)
#pragma unroll
      for (int q = 0; q < 4; ++q) acc[i][j][q] = 0.f;

  stage_half(Ab,                           T_, lds256,                     wave, lane);
  stage_half(Bb,                           T_, lds256 + 16384,             wave, lane);
  stage_half(Bb + (size_t)128 * T_,        T_, lds256 + 16384 + 8192,      wave, lane);
  stage_half(Ab + 64,                      T_, lds256 + 8192,              wave, lane);
  stage_half(Bb + 64,                      T_, lds256 + 16384 + 2 * 8192,  wave, lane);
  stage_half(Bb + (size_t)128 * T_ + 64,   T_, lds256 + 16384 + 3 * 8192,  wave, lane);
  asm volatile("s_waitcnt vmcnt(6)" ::: "memory");
  SB0(); BAR(); SB0();

  for (int t = 0; t < ktiles; ++t) {
    const int d = t & 1;
    const unsigned short* Ah = lds256 + d * 8192;
    const unsigned short* Bh = lds256 + 16384 + (d * 2 + (wn >> 1)) * 8192;
    bf8_t bfr[4][2], af[4][2];
#pragma unroll
    for (int nf = 0; nf < 4; ++nf)
#pragma unroll
      for (int ks = 0; ks < 2; ++ks)
        bfr[nf][ks] = read_frag(Bh, (wn & 1) * 64 + nf * 16 + arow, ks, lane);
#pragma unroll
    for (int mf = 0; mf < 4; ++mf)
#pragma unroll
      for (int ks = 0; ks < 2; ++ks)
        af[mf][ks] = read_frag(Ah, wm * 64 + mf * 16 + arow, ks, lane);
    SB0(); BAR(); SB0();
    MFMA_Q8(0);
    SB0();
    asm volatile("s_waitcnt lgkmcnt(0)" ::: "memory");
    SB0(); BAR(); SB0();
    if (t < ktiles - 2) {
      stage_half(Ab + (size_t)(t + 2) * 64, T_, lds256 + d * 8192, wave, lane);
      stage_half(Bb + (size_t)(t + 2) * 64, T_, lds256 + 16384 + (d * 2) * 8192, wave, lane);
    }
    SB0(); BAR(); SB0();
    MFMA_Q8(1);
    SB0(); BAR(); SB0();
    if (t < ktiles - 2)
      stage_half(Bb + (size_t)128 * T_ + (size_t)(t + 2) * 64, T_, lds256 + 16384 + (d * 2 + 1) * 8192, wave, lane);
    SB0(); BAR(); SB0();
    MFMA_Q8(2);
    SB0(); BAR(); SB0();
    if (t < ktiles - 2)      { asm volatile("s_waitcnt vmcnt(6)" ::: "memory"); }
    else if (t == ktiles - 2){ asm volatile("s_waitcnt vmcnt(0)" ::: "memory"); }
    SB0(); BAR(); SB0();
    MFMA_Q8(3);
    SB0(); BAR(); SB0();
  }

  const int cc = lane & 15, cr4 = (lane >> 4) << 2;
#pragma unroll
  for (int mf = 0; mf < 4; ++mf)
#pragma unroll
    for (int nf = 0; nf < 4; ++nf)
#pragma unroll
      for (int q = 0; q < 4; ++q) {
        const int row = wm * 64 + mf * 16 + cr4 + q;
        const int col = wn * 64 + nf * 16 + cc;
        Cb[(size_t)row * ND_ + col] = acc[mf][nf][q];
      }
}

__global__ void __launch_bounds__(512, 2)
gemm_pv256_kernel(const unsigned short* __restrict__ Pb,
                  const unsigned short* __restrict__ Vt,
                  float* __restrict__ out) {
  extern __shared__ unsigned short lds256[];
  const int b = blockIdx.x & 7;
  const int pair = (blockIdx.x >> 3) & 7;
  const int ncol = blockIdx.x >> 6;
  const int tid = threadIdx.x, lane = tid & 63, wave = tid >> 6;
  const int tbs[2] = {pair, 15 - pair};
#pragma unroll
  for (int si = 0; si < 2; ++si) {
    const int tb = tbs[si];
    const int ktiles = 2 * tb + 2;
    pv_segment(Pb + (size_t)b * T_ * T_ + (size_t)tb * 128 * T_,
               Vt + (size_t)b * ND_ * T_ + (size_t)ncol * 256 * T_,
               out + (size_t)b * T_ * ND_ + (size_t)tb * 128 * ND_ + ncol * 256,
               ktiles, lds256, lane, wave);
  }
}

extern "C" void kernel_launch(void* const* d_in, const int* in_sizes, int n_in,
                              void* d_out, int out_size, void* d_ws, size_t ws_size,
                              hipStream_t stream) {
  const float* X  = (const float*)d_in[0];
  const float* Wq = (const float*)d_in[1];
  const float* Wk = (const float*)d_in[2];
  const float* Wv = (const float*)d_in[3];
  float* out = (float*)d_out;
  (void)in_sizes; (void)n_in; (void)out_size;

  char* ws = (char*)d_ws;
  size_t off = 0;
  auto alloc = [&](size_t bytes) {
    void* p = ws + off;
    off += (bytes + 255) & ~(size_t)255;
    return p;
  };
  unsigned short* Xb  = (unsigned short*)alloc((size_t)B_ * T_ * EMB_ * 2);
  unsigned short* Wtq = (unsigned short*)alloc((size_t)ND_ * EMB_ * 2);
  unsigned short* Wtk = (unsigned short*)alloc((size_t)ND_ * EMB_ * 2);
  unsigned short* Wtv = (unsigned short*)alloc((size_t)ND_ * EMB_ * 2);
  unsigned short* Qb  = (unsigned short*)alloc((size_t)B_ * T_ * ND_ * 2);
  unsigned short* Kb  = (unsigned short*)alloc((size_t)B_ * T_ * ND_ * 2);
  unsigned short* Vt  = (unsigned short*)alloc((size_t)B_ * ND_ * T_ * 2);
  float* colinv = (float*)alloc((size_t)B_ * T_ * 4);
  float* pm     = (float*)alloc((size_t)B_ * 8 * 16 * 256 * 4);
  unsigned short* Pb  = (unsigned short*)alloc((size_t)B_ * T_ * T_ * 2);
  if (off > ws_size) return;

  hipFuncSetAttribute((const void*)&gemm_xw256_kernel<0>,
                      hipFuncAttributeMaxDynamicSharedMemorySize, 131072);
  hipFuncSetAttribute((const void*)&gemm_xw256_kernel<1>,
                      hipFuncAttributeMaxDynamicSharedMemorySize, 131072);
  hipFuncSetAttribute((const void*)&scoretile576_kernel,
                      hipFuncAttributeMaxDynamicSharedMemorySize, 98304);
  hipFuncSetAttribute((const void*)&gemm_pv256_kernel,
                      hipFuncAttributeMaxDynamicSharedMemorySize, 98304);

  hipLaunchKernelGGL(cvt_x_kernel, dim3((B_ * T_ * EMB_) / 1024), dim3(256), 0, stream, X, Xb);
  hipLaunchKernelGGL(transpose_w_kernel, dim3(32, 32), dim3(256), 0, stream, Wq, Wtq, 0.03125f);
  hipLaunchKernelGGL(transpose_w_kernel, dim3(32, 32), dim3(256), 0, stream, Wk, Wtk, 1.0f);
  hipLaunchKernelGGL(transpose_w_kernel, dim3(32, 32), dim3(256), 0, stream, Wv, Wtv, 1.0f);
  hipLaunchKernelGGL((gemm_xw256_kernel<0>), dim3(ND_ / 256, (B_ * T_) / 256), dim3(512), 131072, stream, Xb, Wtq, Qb);
  hipLaunchKernelGGL((gemm_xw256_kernel<0>), dim3(ND_ / 256, (B_ * T_) / 256), dim3(512), 131072, stream, Xb, Wtk, Kb);
  hipLaunchKernelGGL((gemm_xw256_kernel<1>), dim3(ND_ / 256, (B_ * T_) / 256), dim3(512), 131072, stream, Xb, Wtv, Vt);
  hipLaunchKernelGGL(scoretile576_kernel, dim3(576), dim3(512), 98304, stream, Qb, Kb, Pb, pm);
  hipLaunchKernelGGL(colreduce_kernel, dim3(8, B_), dim3(256), 0, stream, pm, colinv);
  hipLaunchKernelGGL(vscale_kernel, dim3((B_ * ND_ * T_) / 8 / 256), dim3(256), 0, stream, Vt, colinv);
  hipLaunchKernelGGL(gemm_pv256_kernel, dim3(NTB2 * 4 * B_), dim3(512), 98304, stream, Pb, Vt, out);
}